// Round 4
// baseline (381.553 us; speedup 1.0000x reference)
//
#include <hip/hip_runtime.h>

#define CAPS_EPS 1e-9f

typedef __fp16 half2_t __attribute__((ext_vector_type(2)));

// One workgroup (256 threads) per output spatial position (b,h,w).
// tid = n*16 + c  (n = output capsule 0..15, c = input channel 0..15, c lane-fast)
// Votes stored PACKED f16x2: V[9][8] half2 = 72 VGPRs (vs 144 f32) -> peak live
// ~115 regs -> __launch_bounds__(256,4) caps at 128 -> 4 waves/SIMD (was 3 at 164).
// All accumulation stays f32 (unpack-fma for s, v_dot2_f32_f16 for b-update).
__global__ __launch_bounds__(256, 4)
void caps_route(const float* __restrict__ poses,   // [4][32][32][16][4][4]
                const float* __restrict__ kern,    // [16][3][3][16][4][4]
                float* __restrict__ out)           // poses 921600 | acts 57600
{
    const int pos = blockIdx.x;            // 0..3599
    const int b   = pos / 900;
    const int hw  = pos % 900;
    const int h   = hw / 30;
    const int w   = hw % 30;

    const int tid = (int)threadIdx.x;
    const int c   = tid & 15;              // input channel (lane-fast)
    const int n   = tid >> 4;              // output capsule

    // pose tile: [k][c][4 float4], granule-swizzled to kill LDS bank conflicts
    __shared__ float4 pose_lds[9 * 64];
    __shared__ float  sb[4 * 9 * 16];      // [wave][k][c] softmax partials

    // ---------------- stage pose blocks (coalesced) ----------------
    for (int idx = tid; idx < 576; idx += 256) {
        const int k  = idx >> 6;           // 0..8
        const int r  = idx & 63;           // float4 index within 1KB segment
        const int cc = r >> 2;
        const int eq = r & 3;
        const int ki = k / 3, kj = k % 3;
        const float4* src = reinterpret_cast<const float4*>(
            poses + (size_t)(((b * 32 + h + ki) * 32) + (w + kj)) * 256);
        pose_lds[k * 64 + cc * 4 + (eq ^ ((cc >> 1) & 3))] = src[r];
    }
    __syncthreads();

    // ---------------- compute votes, pack to f16 pairs ----------------
    // Vp[k][p*2+rh] = (V[k][p*4+2rh], V[k][p*4+2rh+1]) as half2
    half2_t Vp[9][8];
    const float* kb = kern + (size_t)n * 2304 + (size_t)c * 16;
    const int swz = (c >> 1) & 3;
    #pragma unroll
    for (int k = 0; k < 9; ++k) {
        float a[16], g[16];
        #pragma unroll
        for (int eq = 0; eq < 4; ++eq) {
            float4 t = pose_lds[k * 64 + c * 4 + (eq ^ swz)];
            a[eq * 4 + 0] = t.x; a[eq * 4 + 1] = t.y;
            a[eq * 4 + 2] = t.z; a[eq * 4 + 3] = t.w;
        }
        #pragma unroll
        for (int eq = 0; eq < 4; ++eq) {
            float4 t = reinterpret_cast<const float4*>(kb + k * 256)[eq];
            g[eq * 4 + 0] = t.x; g[eq * 4 + 1] = t.y;
            g[eq * 4 + 2] = t.z; g[eq * 4 + 3] = t.w;
        }
        #pragma unroll
        for (int p = 0; p < 4; ++p) {
            #pragma unroll
            for (int rh = 0; rh < 2; ++rh) {
                const int r0 = 2 * rh, r1 = 2 * rh + 1;
                float acc0 = a[p * 4 + 0] * g[0 * 4 + r0];
                float acc1 = a[p * 4 + 0] * g[0 * 4 + r1];
                acc0 = fmaf(a[p * 4 + 1], g[1 * 4 + r0], acc0);
                acc1 = fmaf(a[p * 4 + 1], g[1 * 4 + r1], acc1);
                acc0 = fmaf(a[p * 4 + 2], g[2 * 4 + r0], acc0);
                acc1 = fmaf(a[p * 4 + 2], g[2 * 4 + r1], acc1);
                acc0 = fmaf(a[p * 4 + 3], g[3 * 4 + r0], acc0);
                acc1 = fmaf(a[p * 4 + 3], g[3 * 4 + r1], acc1);
                Vp[k][p * 2 + rh] = __builtin_amdgcn_cvt_pkrtz(acc0, acc1);
            }
        }
    }

    // ---------------- dynamic routing (3 iterations) ----------------
    float b_log[9];
    #pragma unroll
    for (int k = 0; k < 9; ++k) b_log[k] = 0.0f;

    float v[16];
    const int wv = tid >> 6;               // wave id 0..3

    for (int it = 0; it < 3; ++it) {
        float ck[9];
        if (it == 0) {
            // softmax of all-zero logits over 16 capsules = 1/16 exactly
            #pragma unroll
            for (int k = 0; k < 9; ++k) ck[k] = 0.0625f;
        } else {
            float eb[9], ebs[9];
            #pragma unroll
            for (int k = 0; k < 9; ++k) { eb[k] = __expf(b_log[k]); ebs[k] = eb[k]; }
            // in-wave partial sum over the wave's 4 n-values (lane bits 4,5)
            #pragma unroll
            for (int k = 0; k < 9; ++k) {
                ebs[k] += __shfl_xor(ebs[k], 16);
                ebs[k] += __shfl_xor(ebs[k], 32);
            }
            __syncthreads();   // protect sb against previous iteration's readers
            if ((tid & 63) < 16) {         // one lane per (wave, c)
                #pragma unroll
                for (int k = 0; k < 9; ++k) sb[(wv * 9 + k) * 16 + c] = ebs[k];
            }
            __syncthreads();
            #pragma unroll
            for (int k = 0; k < 9; ++k) {
                const float tot = sb[(0 * 9 + k) * 16 + c] + sb[(1 * 9 + k) * 16 + c]
                                + sb[(2 * 9 + k) * 16 + c] + sb[(3 * 9 + k) * 16 + c];
                ck[k] = eb[k] / tot;
            }
        }

        // s partial over this thread's 9 votes (unpack f16 -> f32 FMA)
        float s[16];
        #pragma unroll
        for (int d = 0; d < 16; ++d) s[d] = 0.0f;
        #pragma unroll
        for (int k = 0; k < 9; ++k) {
            const float ckk = ck[k];
            #pragma unroll
            for (int j = 0; j < 8; ++j) {
                half2_t pk = Vp[k][j];
                s[2 * j]     = fmaf(ckk, (float)pk.x, s[2 * j]);
                s[2 * j + 1] = fmaf(ckk, (float)pk.y, s[2 * j + 1]);
            }
        }
        // butterfly all-reduce over c (lane bits 0..3) -> every lane holds s[n][:]
        #pragma unroll
        for (int m = 1; m <= 8; m <<= 1) {
            #pragma unroll
            for (int d = 0; d < 16; ++d) s[d] += __shfl_xor(s[d], m);
        }
        // squash (in-registers, redundant across the 16 c-lanes)
        float n2 = 0.0f;
        #pragma unroll
        for (int d = 0; d < 16; ++d) n2 = fmaf(s[d], s[d], n2);
        const float scale = n2 / ((1.0f + n2) * sqrtf(n2 + CAPS_EPS));
        #pragma unroll
        for (int d = 0; d < 16; ++d) v[d] = s[d] * scale;

        if (it < 2) {   // final b-update is dead in the reference
            half2_t vpk[8];
            #pragma unroll
            for (int j = 0; j < 8; ++j)
                vpk[j] = __builtin_amdgcn_cvt_pkrtz(v[2 * j], v[2 * j + 1]);
            #pragma unroll
            for (int k = 0; k < 9; ++k) {
                float dot = 0.0f;
                #pragma unroll
                for (int j = 0; j < 8; ++j)
                    dot = __builtin_amdgcn_fdot2(Vp[k][j], vpk[j], dot, false);
                b_log[k] += dot;
            }
        }
    }

    // ---------------- outputs ----------------
    if (c == 0) {
        float4* dst = reinterpret_cast<float4*>(out + (size_t)pos * 256 + n * 16);
        dst[0] = make_float4(v[0],  v[1],  v[2],  v[3]);
        dst[1] = make_float4(v[4],  v[5],  v[6],  v[7]);
        dst[2] = make_float4(v[8],  v[9],  v[10], v[11]);
        dst[3] = make_float4(v[12], v[13], v[14], v[15]);

        float m2 = 0.0f;
        #pragma unroll
        for (int d = 0; d < 16; ++d) m2 = fmaf(v[d], v[d], m2);
        const float sc2 = m2 / ((1.0f + m2) * sqrtf(m2 + CAPS_EPS));
        out[921600 + (size_t)pos * 16 + n] = sqrtf(m2 * sc2 * sc2 + CAPS_EPS);
    }
}

extern "C" void kernel_launch(void* const* d_in, const int* in_sizes, int n_in,
                              void* d_out, int out_size, void* d_ws, size_t ws_size,
                              hipStream_t stream) {
    const float* poses = (const float*)d_in[0];
    // d_in[1] = input_activations: unused by the reference computation
    const float* kern  = (const float*)d_in[2];
    float* out = (float*)d_out;

    caps_route<<<dim3(3600), dim3(256), 0, stream>>>(poses, kern, out);
}

// Round 5
// 106.527 us; speedup vs baseline: 3.5817x; 3.5817x over previous
//
#include <hip/hip_runtime.h>

#define CAPS_EPS 1e-9f

typedef __fp16 half2_t __attribute__((ext_vector_type(2)));

// One workgroup (256 threads) per output spatial position (b,h,w).
// tid = n*16 + c  (n = output capsule 0..15, c = input channel 0..15, c lane-fast)
// Votes stored PACKED f16x2: Vp[9][8] half2 = 72 VGPRs. All accumulation f32.
// EMPIRICAL launch_bounds mapping on this compiler: (256,N) caps VGPR at 256/N:
//   N=1 -> natural 164 (r2: 157us), N=2 -> 128, N=4 -> 64 (r4: total spill, 381us).
// f16 kernel's natural live set ~115 -> (256,2)/cap-128 fits with zero spill,
// giving 4 waves/SIMD (vs 3 at 164 regs).
__global__ __launch_bounds__(256, 2)
void caps_route(const float* __restrict__ poses,   // [4][32][32][16][4][4]
                const float* __restrict__ kern,    // [16][3][3][16][4][4]
                float* __restrict__ out)           // poses 921600 | acts 57600
{
    const int pos = blockIdx.x;            // 0..3599
    const int b   = pos / 900;
    const int hw  = pos % 900;
    const int h   = hw / 30;
    const int w   = hw % 30;

    const int tid = (int)threadIdx.x;
    const int c   = tid & 15;              // input channel (lane-fast)
    const int n   = tid >> 4;              // output capsule

    // pose tile: [k][c][4 float4], granule-swizzled to kill LDS bank conflicts
    __shared__ float4 pose_lds[9 * 64];
    __shared__ float  sb[4 * 9 * 16];      // [wave][k][c] softmax partials

    // ---------------- stage pose blocks (coalesced) ----------------
    for (int idx = tid; idx < 576; idx += 256) {
        const int k  = idx >> 6;           // 0..8
        const int r  = idx & 63;           // float4 index within 1KB segment
        const int cc = r >> 2;
        const int eq = r & 3;
        const int ki = k / 3, kj = k % 3;
        const float4* src = reinterpret_cast<const float4*>(
            poses + (size_t)(((b * 32 + h + ki) * 32) + (w + kj)) * 256);
        pose_lds[k * 64 + cc * 4 + (eq ^ ((cc >> 1) & 3))] = src[r];
    }
    __syncthreads();

    // ---------------- compute votes, pack to f16 pairs ----------------
    // Vp[k][p*2+rh] = (V[k][p*4+2rh], V[k][p*4+2rh+1]) as half2
    half2_t Vp[9][8];
    const float* kb = kern + (size_t)n * 2304 + (size_t)c * 16;
    const int swz = (c >> 1) & 3;
    #pragma unroll
    for (int k = 0; k < 9; ++k) {
        float a[16], g[16];
        #pragma unroll
        for (int eq = 0; eq < 4; ++eq) {
            float4 t = pose_lds[k * 64 + c * 4 + (eq ^ swz)];
            a[eq * 4 + 0] = t.x; a[eq * 4 + 1] = t.y;
            a[eq * 4 + 2] = t.z; a[eq * 4 + 3] = t.w;
        }
        #pragma unroll
        for (int eq = 0; eq < 4; ++eq) {
            float4 t = reinterpret_cast<const float4*>(kb + k * 256)[eq];
            g[eq * 4 + 0] = t.x; g[eq * 4 + 1] = t.y;
            g[eq * 4 + 2] = t.z; g[eq * 4 + 3] = t.w;
        }
        #pragma unroll
        for (int p = 0; p < 4; ++p) {
            #pragma unroll
            for (int rh = 0; rh < 2; ++rh) {
                const int r0 = 2 * rh, r1 = 2 * rh + 1;
                float acc0 = a[p * 4 + 0] * g[0 * 4 + r0];
                float acc1 = a[p * 4 + 0] * g[0 * 4 + r1];
                acc0 = fmaf(a[p * 4 + 1], g[1 * 4 + r0], acc0);
                acc1 = fmaf(a[p * 4 + 1], g[1 * 4 + r1], acc1);
                acc0 = fmaf(a[p * 4 + 2], g[2 * 4 + r0], acc0);
                acc1 = fmaf(a[p * 4 + 2], g[2 * 4 + r1], acc1);
                acc0 = fmaf(a[p * 4 + 3], g[3 * 4 + r0], acc0);
                acc1 = fmaf(a[p * 4 + 3], g[3 * 4 + r1], acc1);
                Vp[k][p * 2 + rh] = __builtin_amdgcn_cvt_pkrtz(acc0, acc1);
            }
        }
    }

    // ---------------- dynamic routing (3 iterations) ----------------
    float b_log[9];
    #pragma unroll
    for (int k = 0; k < 9; ++k) b_log[k] = 0.0f;

    float v[16];
    const int wv = tid >> 6;               // wave id 0..3

    for (int it = 0; it < 3; ++it) {
        float ck[9];
        if (it == 0) {
            // softmax of all-zero logits over 16 capsules = 1/16 exactly
            #pragma unroll
            for (int k = 0; k < 9; ++k) ck[k] = 0.0625f;
        } else {
            float eb[9], ebs[9];
            #pragma unroll
            for (int k = 0; k < 9; ++k) { eb[k] = __expf(b_log[k]); ebs[k] = eb[k]; }
            // in-wave partial sum over the wave's 4 n-values (lane bits 4,5)
            #pragma unroll
            for (int k = 0; k < 9; ++k) {
                ebs[k] += __shfl_xor(ebs[k], 16);
                ebs[k] += __shfl_xor(ebs[k], 32);
            }
            __syncthreads();   // protect sb against previous iteration's readers
            if ((tid & 63) < 16) {         // one lane per (wave, c)
                #pragma unroll
                for (int k = 0; k < 9; ++k) sb[(wv * 9 + k) * 16 + c] = ebs[k];
            }
            __syncthreads();
            #pragma unroll
            for (int k = 0; k < 9; ++k) {
                const float tot = sb[(0 * 9 + k) * 16 + c] + sb[(1 * 9 + k) * 16 + c]
                                + sb[(2 * 9 + k) * 16 + c] + sb[(3 * 9 + k) * 16 + c];
                ck[k] = eb[k] / tot;
            }
        }

        // s partial over this thread's 9 votes (unpack f16 -> f32 FMA)
        float s[16];
        #pragma unroll
        for (int d = 0; d < 16; ++d) s[d] = 0.0f;
        #pragma unroll
        for (int k = 0; k < 9; ++k) {
            const float ckk = ck[k];
            #pragma unroll
            for (int j = 0; j < 8; ++j) {
                half2_t pk = Vp[k][j];
                s[2 * j]     = fmaf(ckk, (float)pk.x, s[2 * j]);
                s[2 * j + 1] = fmaf(ckk, (float)pk.y, s[2 * j + 1]);
            }
        }
        // butterfly all-reduce over c (lane bits 0..3) -> every lane holds s[n][:]
        #pragma unroll
        for (int m = 1; m <= 8; m <<= 1) {
            #pragma unroll
            for (int d = 0; d < 16; ++d) s[d] += __shfl_xor(s[d], m);
        }
        // squash (in-registers, redundant across the 16 c-lanes)
        float n2 = 0.0f;
        #pragma unroll
        for (int d = 0; d < 16; ++d) n2 = fmaf(s[d], s[d], n2);
        const float scale = n2 / ((1.0f + n2) * sqrtf(n2 + CAPS_EPS));
        #pragma unroll
        for (int d = 0; d < 16; ++d) v[d] = s[d] * scale;

        if (it < 2) {   // final b-update is dead in the reference
            half2_t vpk[8];
            #pragma unroll
            for (int j = 0; j < 8; ++j)
                vpk[j] = __builtin_amdgcn_cvt_pkrtz(v[2 * j], v[2 * j + 1]);
            #pragma unroll
            for (int k = 0; k < 9; ++k) {
                float dot = 0.0f;
                #pragma unroll
                for (int j = 0; j < 8; ++j)
                    dot = __builtin_amdgcn_fdot2(Vp[k][j], vpk[j], dot, false);
                b_log[k] += dot;
            }
        }
    }

    // ---------------- outputs ----------------
    if (c == 0) {
        float4* dst = reinterpret_cast<float4*>(out + (size_t)pos * 256 + n * 16);
        dst[0] = make_float4(v[0],  v[1],  v[2],  v[3]);
        dst[1] = make_float4(v[4],  v[5],  v[6],  v[7]);
        dst[2] = make_float4(v[8],  v[9],  v[10], v[11]);
        dst[3] = make_float4(v[12], v[13], v[14], v[15]);

        float m2 = 0.0f;
        #pragma unroll
        for (int d = 0; d < 16; ++d) m2 = fmaf(v[d], v[d], m2);
        const float sc2 = m2 / ((1.0f + m2) * sqrtf(m2 + CAPS_EPS));
        out[921600 + (size_t)pos * 16 + n] = sqrtf(m2 * sc2 * sc2 + CAPS_EPS);
    }
}

extern "C" void kernel_launch(void* const* d_in, const int* in_sizes, int n_in,
                              void* d_out, int out_size, void* d_ws, size_t ws_size,
                              hipStream_t stream) {
    const float* poses = (const float*)d_in[0];
    // d_in[1] = input_activations: unused by the reference computation
    const float* kern  = (const float*)d_in[2];
    float* out = (float*)d_out;

    caps_route<<<dim3(3600), dim3(256), 0, stream>>>(poses, kern, out);
}

// Round 6
// 99.530 us; speedup vs baseline: 3.8335x; 1.0703x over previous
//
#include <hip/hip_runtime.h>

#define CAPS_EPS 1e-9f

typedef __fp16 half2_t __attribute__((ext_vector_type(2)));

__device__ __forceinline__ half2_t bc_h2(float f) {
    union { float f; half2_t h; } u; u.f = f; return u.h;
}
__device__ __forceinline__ float bc_f(half2_t h) {
    union { float f; half2_t h; } u; u.h = h; return u.f;
}

// ---------------------------------------------------------------------------
// Pre-pass: pack kernel weights f32 -> f16 q-pairs for v_dot2_f32_f16.
// wpk[((n*9+k)*16+c)*8 + r*2 + qh] = (W[n,k,c,2qh,r], W[n,k,c,2qh+1,r])
// 36864 half2 outputs = 147456 B read, 73728 B written (runs in ~2 us).
// ---------------------------------------------------------------------------
__global__ __launch_bounds__(256)
void pack_weights(const float* __restrict__ kern, half2_t* __restrict__ wpk) {
    const int t  = blockIdx.x * 256 + (int)threadIdx.x;   // 0..36863
    const int qh = t & 1;
    const int r  = (t >> 1) & 3;
    const int base = (t >> 3) * 16;                       // ((n*9+k)*16+c)*16
    const float f0 = kern[base + (2 * qh) * 4 + r];
    const float f1 = kern[base + (2 * qh + 1) * 4 + r];
    wpk[t] = __builtin_amdgcn_cvt_pkrtz(f0, f1);
}

// ---------------------------------------------------------------------------
// One workgroup (256 threads) per output spatial position.
// tid = n*16 + c. Votes f16-packed Vp[9][8]; vote matmul via v_dot2_f32_f16
// (f16 inputs, f32 accumulate). Softmax LDS double-buffered (1 barrier/iter).
// Empirical: __launch_bounds__(256,2) -> VGPR cap 128 -> 4 waves/SIMD, no spill.
// ---------------------------------------------------------------------------
__global__ __launch_bounds__(256, 2)
void caps_route(const float* __restrict__ poses,    // [4][32][32][16][4][4]
                const half2_t* __restrict__ wpk,    // packed weights (pre-pass)
                float* __restrict__ out)            // poses 921600 | acts 57600
{
    const int pos = blockIdx.x;            // 0..3599
    const int b   = pos / 900;
    const int hw  = pos % 900;
    const int h   = hw / 30;
    const int w   = hw % 30;

    const int tid = (int)threadIdx.x;
    const int c   = tid & 15;              // input channel (lane-fast)
    const int n   = tid >> 4;              // output capsule

    // pose tile, f16 q-pairs: [k][p-half][c] float4 = {pEven(q01,q23), pOdd(q01,q23)}
    // reads: 16 c-lanes stride 16B -> 2-way bank alias (free), no swizzle needed.
    __shared__ float4 poseH[9 * 32];
    __shared__ float  sb[2][4 * 9 * 16];   // double-buffered softmax partials

    // ---------------- stage pose blocks, cvt to f16 (coalesced) ----------------
    for (int idx = tid; idx < 288; idx += 256) {
        const int k   = idx >> 5;          // 0..8
        const int rem = idx & 31;
        const int hh  = rem >> 4;          // p-half: 0 -> p0,p1 ; 1 -> p2,p3
        const int cc  = rem & 15;
        const int ki = k / 3, kj = k % 3;
        const float4* src = reinterpret_cast<const float4*>(
            poses + (size_t)(((b * 32 + h + ki) * 32) + (w + kj)) * 256);
        const float4 t0 = src[cc * 4 + hh * 2];
        const float4 t1 = src[cc * 4 + hh * 2 + 1];
        float4 o;
        o.x = bc_f(__builtin_amdgcn_cvt_pkrtz(t0.x, t0.y));
        o.y = bc_f(__builtin_amdgcn_cvt_pkrtz(t0.z, t0.w));
        o.z = bc_f(__builtin_amdgcn_cvt_pkrtz(t1.x, t1.y));
        o.w = bc_f(__builtin_amdgcn_cvt_pkrtz(t1.z, t1.w));
        poseH[k * 32 + hh * 16 + cc] = o;
    }
    __syncthreads();

    // ---------------- votes via dot2 (f16 in, f32 acc), pack to f16 ----------------
    half2_t Vp[9][8];
    const half2_t* wb = wpk + (size_t)n * 1152 + c * 8;   // ((n*9+k)*16+c)*8
    #pragma unroll
    for (int k = 0; k < 9; ++k) {
        const float4 t0 = poseH[k * 32 + c];
        const float4 t1 = poseH[k * 32 + 16 + c];
        const float4* gp = reinterpret_cast<const float4*>(wb + (size_t)k * 128);
        const float4 g0 = gp[0], g1 = gp[1];
        half2_t ap[4][2] = {   // [p][qh]
            {bc_h2(t0.x), bc_h2(t0.y)}, {bc_h2(t0.z), bc_h2(t0.w)},
            {bc_h2(t1.x), bc_h2(t1.y)}, {bc_h2(t1.z), bc_h2(t1.w)} };
        half2_t ga[4][2] = {   // [r][qh]
            {bc_h2(g0.x), bc_h2(g0.y)}, {bc_h2(g0.z), bc_h2(g0.w)},
            {bc_h2(g1.x), bc_h2(g1.y)}, {bc_h2(g1.z), bc_h2(g1.w)} };
        #pragma unroll
        for (int p = 0; p < 4; ++p) {
            #pragma unroll
            for (int rh = 0; rh < 2; ++rh) {
                float a0 = __builtin_amdgcn_fdot2(ap[p][0], ga[2 * rh][0], 0.0f, false);
                a0 = __builtin_amdgcn_fdot2(ap[p][1], ga[2 * rh][1], a0, false);
                float a1 = __builtin_amdgcn_fdot2(ap[p][0], ga[2 * rh + 1][0], 0.0f, false);
                a1 = __builtin_amdgcn_fdot2(ap[p][1], ga[2 * rh + 1][1], a1, false);
                Vp[k][p * 2 + rh] = __builtin_amdgcn_cvt_pkrtz(a0, a1);
            }
        }
    }

    // ---------------- dynamic routing (3 iterations) ----------------
    float b_log[9];
    #pragma unroll
    for (int k = 0; k < 9; ++k) b_log[k] = 0.0f;

    float v[16];
    const int wv = tid >> 6;               // wave id 0..3

    for (int it = 0; it < 3; ++it) {
        float ck[9];
        if (it == 0) {
            // softmax of all-zero logits over 16 capsules = 1/16 exactly
            #pragma unroll
            for (int k = 0; k < 9; ++k) ck[k] = 0.0625f;
        } else {
            const int buf = it - 1;        // double-buffer: no pre-write barrier
            float eb[9], ebs[9];
            #pragma unroll
            for (int k = 0; k < 9; ++k) { eb[k] = __expf(b_log[k]); ebs[k] = eb[k]; }
            // in-wave partial sum over the wave's 4 n-values (lane bits 4,5)
            #pragma unroll
            for (int k = 0; k < 9; ++k) {
                ebs[k] += __shfl_xor(ebs[k], 16);
                ebs[k] += __shfl_xor(ebs[k], 32);
            }
            if ((tid & 63) < 16) {         // one lane per (wave, c)
                #pragma unroll
                for (int k = 0; k < 9; ++k) sb[buf][(wv * 9 + k) * 16 + c] = ebs[k];
            }
            __syncthreads();
            #pragma unroll
            for (int k = 0; k < 9; ++k) {
                const float tot = sb[buf][(0 * 9 + k) * 16 + c] + sb[buf][(1 * 9 + k) * 16 + c]
                                + sb[buf][(2 * 9 + k) * 16 + c] + sb[buf][(3 * 9 + k) * 16 + c];
                ck[k] = eb[k] / tot;
            }
        }

        // s partial over this thread's 9 votes (f16 unpack -> f32 FMA / fma_mix)
        float s[16];
        #pragma unroll
        for (int d = 0; d < 16; ++d) s[d] = 0.0f;
        #pragma unroll
        for (int k = 0; k < 9; ++k) {
            const float ckk = ck[k];
            #pragma unroll
            for (int j = 0; j < 8; ++j) {
                half2_t pk = Vp[k][j];
                s[2 * j]     = fmaf(ckk, (float)pk.x, s[2 * j]);
                s[2 * j + 1] = fmaf(ckk, (float)pk.y, s[2 * j + 1]);
            }
        }
        // butterfly all-reduce over c (lane bits 0..3) -> every lane holds s[n][:]
        #pragma unroll
        for (int m = 1; m <= 8; m <<= 1) {
            #pragma unroll
            for (int d = 0; d < 16; ++d) s[d] += __shfl_xor(s[d], m);
        }
        // squash (in-registers, redundant across the 16 c-lanes)
        float n2 = 0.0f;
        #pragma unroll
        for (int d = 0; d < 16; ++d) n2 = fmaf(s[d], s[d], n2);
        const float scale = n2 / ((1.0f + n2) * sqrtf(n2 + CAPS_EPS));
        #pragma unroll
        for (int d = 0; d < 16; ++d) v[d] = s[d] * scale;

        if (it < 2) {   // final b-update is dead in the reference
            half2_t vpk[8];
            #pragma unroll
            for (int j = 0; j < 8; ++j)
                vpk[j] = __builtin_amdgcn_cvt_pkrtz(v[2 * j], v[2 * j + 1]);
            #pragma unroll
            for (int k = 0; k < 9; ++k) {
                float dot = 0.0f;
                #pragma unroll
                for (int j = 0; j < 8; ++j)
                    dot = __builtin_amdgcn_fdot2(Vp[k][j], vpk[j], dot, false);
                b_log[k] += dot;
            }
        }
    }

    // ---------------- outputs ----------------
    if (c == 0) {
        float4* dst = reinterpret_cast<float4*>(out + (size_t)pos * 256 + n * 16);
        dst[0] = make_float4(v[0],  v[1],  v[2],  v[3]);
        dst[1] = make_float4(v[4],  v[5],  v[6],  v[7]);
        dst[2] = make_float4(v[8],  v[9],  v[10], v[11]);
        dst[3] = make_float4(v[12], v[13], v[14], v[15]);

        float m2 = 0.0f;
        #pragma unroll
        for (int d = 0; d < 16; ++d) m2 = fmaf(v[d], v[d], m2);
        const float sc2 = m2 / ((1.0f + m2) * sqrtf(m2 + CAPS_EPS));
        out[921600 + (size_t)pos * 16 + n] = sqrtf(m2 * sc2 * sc2 + CAPS_EPS);
    }
}

extern "C" void kernel_launch(void* const* d_in, const int* in_sizes, int n_in,
                              void* d_out, int out_size, void* d_ws, size_t ws_size,
                              hipStream_t stream) {
    const float* poses = (const float*)d_in[0];
    // d_in[1] = input_activations: unused by the reference computation
    const float* kern  = (const float*)d_in[2];
    float* out = (float*)d_out;
    half2_t* wpk = (half2_t*)d_ws;         // 73728 B of scratch

    pack_weights<<<dim3(144), dim3(256), 0, stream>>>(kern, wpk);
    caps_route<<<dim3(3600), dim3(256), 0, stream>>>(poses, wpk, out);
}

// Round 8
// 78.171 us; speedup vs baseline: 4.8810x; 1.2732x over previous
//
#include <hip/hip_runtime.h>

#define CAPS_EPS 1e-9f

typedef __fp16 half2_t __attribute__((ext_vector_type(2)));

__device__ __forceinline__ half2_t bc_h2(float f) {
    union { float f; half2_t h; } u; u.f = f; return u.h;
}
__device__ __forceinline__ float bc_f(half2_t h) {
    union { float f; half2_t h; } u; u.h = h; return u.f;
}

// DPP cross-lane: xor1=quad_perm(1,0,3,2)=0xB1, xor2=quad_perm(2,3,0,1)=0x4E,
// xor8=row_ror:8=0x128 (all within 16-lane rows -> pure VALU, no LDS pipe).
// xor4 is not a DPP row perm -> ds_swizzle bitmode 0x101F. xor16 -> 0x401F.
template<int CTRL>
__device__ __forceinline__ float mov_dpp_f(float x) {
    return __builtin_bit_cast(float,
        __builtin_amdgcn_update_dpp(0, __builtin_bit_cast(int, x), CTRL, 0xF, 0xF, true));
}
template<int PAT>
__device__ __forceinline__ float mov_sw_f(float x) {
    return __builtin_bit_cast(float,
        __builtin_amdgcn_ds_swizzle(__builtin_bit_cast(int, x), PAT));
}
template<int CTRL>
__device__ __forceinline__ float xadd_dpp(float x) { return x + mov_dpp_f<CTRL>(x); }
__device__ __forceinline__ float xadd_sw4(float x) { return x + mov_sw_f<0x101F>(x); }

// ---------------------------------------------------------------------------
// Pre-pass: pack kernel weights f32 -> f16 q-pairs for v_dot2_f32_f16.
// wpk[((n*9+k)*16+c)*8 + r*2 + qh] = (W[n,k,c,2qh,r], W[n,k,c,2qh+1,r])
// ---------------------------------------------------------------------------
__global__ __launch_bounds__(256)
void pack_weights(const float* __restrict__ kern, half2_t* __restrict__ wpk) {
    const int t  = blockIdx.x * 256 + (int)threadIdx.x;   // 0..36863
    const int qh = t & 1;
    const int r  = (t >> 1) & 3;
    const int base = (t >> 3) * 16;                       // ((n*9+k)*16+c)*16
    const float f0 = kern[base + (2 * qh) * 4 + r];
    const float f1 = kern[base + (2 * qh + 1) * 4 + r];
    wpk[t] = __builtin_amdgcn_cvt_pkrtz(f0, f1);
}

// ---------------------------------------------------------------------------
// One workgroup (256 threads) per output spatial position. tid = n*16 + c.
// Votes f16-packed Vp[9][8]; vote matmul via v_dot2_f32_f16 (f32 accumulate).
// Cross-lane reduces on DPP (VALU) where possible; iter-2 uses reduce-scatter
// (lane c keeps s[c]) -> coalesced per-lane pose store, no allgather.
// Empirical: __launch_bounds__(256,2) -> VGPR cap 128 -> 4 waves/SIMD, no spill.
// ---------------------------------------------------------------------------
__global__ __launch_bounds__(256, 2)
void caps_route(const float* __restrict__ poses,    // [4][32][32][16][4][4]
                const half2_t* __restrict__ wpk,    // packed weights (pre-pass)
                float* __restrict__ out)            // poses 921600 | acts 57600
{
    const int pos = blockIdx.x;            // 0..3599
    const int b   = pos / 900;
    const int hw  = pos % 900;
    const int h   = hw / 30;
    const int w   = hw % 30;

    const int tid = (int)threadIdx.x;
    const int c   = tid & 15;              // input channel (lane-fast)
    const int n   = tid >> 4;              // output capsule

    __shared__ float4 poseH[9 * 32];       // f16 q-pairs: [k][p-half][c]
    __shared__ float  sb[2][4 * 9 * 16];   // softmax partials (buf per routing iter)

    // ---------------- stage pose blocks, cvt to f16 (coalesced) ----------------
    for (int idx = tid; idx < 288; idx += 256) {
        const int k   = idx >> 5;          // 0..8
        const int rem = idx & 31;
        const int hh  = rem >> 4;          // p-half
        const int cc  = rem & 15;
        const int ki = k / 3, kj = k % 3;
        const float4* src = reinterpret_cast<const float4*>(
            poses + (size_t)(((b * 32 + h + ki) * 32) + (w + kj)) * 256);
        const float4 t0 = src[cc * 4 + hh * 2];
        const float4 t1 = src[cc * 4 + hh * 2 + 1];
        float4 o;
        o.x = bc_f(__builtin_amdgcn_cvt_pkrtz(t0.x, t0.y));
        o.y = bc_f(__builtin_amdgcn_cvt_pkrtz(t0.z, t0.w));
        o.z = bc_f(__builtin_amdgcn_cvt_pkrtz(t1.x, t1.y));
        o.w = bc_f(__builtin_amdgcn_cvt_pkrtz(t1.z, t1.w));
        poseH[k * 32 + hh * 16 + cc] = o;
    }
    __syncthreads();

    // ---------------- votes via dot2 (f16 in, f32 acc), pack to f16 ----------------
    half2_t Vp[9][8];
    const half2_t* wb = wpk + (size_t)n * 1152 + c * 8;
    #pragma unroll
    for (int k = 0; k < 9; ++k) {
        const float4 t0 = poseH[k * 32 + c];
        const float4 t1 = poseH[k * 32 + 16 + c];
        const float4* gp = reinterpret_cast<const float4*>(wb + (size_t)k * 128);
        const float4 g0 = gp[0], g1 = gp[1];
        half2_t ap[4][2] = {
            {bc_h2(t0.x), bc_h2(t0.y)}, {bc_h2(t0.z), bc_h2(t0.w)},
            {bc_h2(t1.x), bc_h2(t1.y)}, {bc_h2(t1.z), bc_h2(t1.w)} };
        half2_t ga[4][2] = {
            {bc_h2(g0.x), bc_h2(g0.y)}, {bc_h2(g0.z), bc_h2(g0.w)},
            {bc_h2(g1.x), bc_h2(g1.y)}, {bc_h2(g1.z), bc_h2(g1.w)} };
        #pragma unroll
        for (int p = 0; p < 4; ++p) {
            #pragma unroll
            for (int rh = 0; rh < 2; ++rh) {
                float a0 = __builtin_amdgcn_fdot2(ap[p][0], ga[2 * rh][0], 0.0f, false);
                a0 = __builtin_amdgcn_fdot2(ap[p][1], ga[2 * rh][1], a0, false);
                float a1 = __builtin_amdgcn_fdot2(ap[p][0], ga[2 * rh + 1][0], 0.0f, false);
                a1 = __builtin_amdgcn_fdot2(ap[p][1], ga[2 * rh + 1][1], a1, false);
                Vp[k][p * 2 + rh] = __builtin_amdgcn_cvt_pkrtz(a0, a1);
            }
        }
    }

    // ---------------- dynamic routing ----------------
    float b_log[9];
    #pragma unroll
    for (int k = 0; k < 9; ++k) b_log[k] = 0.0f;

    const int wv = tid >> 6;               // wave id 0..3

    // -------- iterations 0,1: full allreduce (b-update needs full v) --------
    for (int it = 0; it < 2; ++it) {
        float ck[9];
        if (it == 0) {
            #pragma unroll
            for (int k = 0; k < 9; ++k) ck[k] = 0.0625f;   // softmax(0) = 1/16
        } else {
            float eb[9], ebs[9];
            #pragma unroll
            for (int k = 0; k < 9; ++k) { eb[k] = __expf(b_log[k]); ebs[k] = eb[k]; }
            #pragma unroll
            for (int k = 0; k < 9; ++k) {
                ebs[k] += mov_sw_f<0x401F>(ebs[k]);        // xor16
                ebs[k] += __shfl_xor(ebs[k], 32);          // cross-half
            }
            if ((tid & 63) < 16) {
                #pragma unroll
                for (int k = 0; k < 9; ++k) sb[0][(wv * 9 + k) * 16 + c] = ebs[k];
            }
            __syncthreads();
            #pragma unroll
            for (int k = 0; k < 9; ++k) {
                const float tot = sb[0][(0 * 9 + k) * 16 + c] + sb[0][(1 * 9 + k) * 16 + c]
                                + sb[0][(2 * 9 + k) * 16 + c] + sb[0][(3 * 9 + k) * 16 + c];
                ck[k] = eb[k] * __builtin_amdgcn_rcpf(tot);
            }
        }

        float s[16];
        #pragma unroll
        for (int d = 0; d < 16; ++d) s[d] = 0.0f;
        #pragma unroll
        for (int k = 0; k < 9; ++k) {
            const float ckk = ck[k];
            #pragma unroll
            for (int j = 0; j < 8; ++j) {
                half2_t pk = Vp[k][j];
                s[2 * j]     = fmaf(ckk, (float)pk.x, s[2 * j]);
                s[2 * j + 1] = fmaf(ckk, (float)pk.y, s[2 * j + 1]);
            }
        }
        // butterfly allreduce over c: DPP for xor1/2/8, ds_swizzle for xor4
        #pragma unroll
        for (int d = 0; d < 16; ++d) s[d] = xadd_dpp<0xB1>(s[d]);
        #pragma unroll
        for (int d = 0; d < 16; ++d) s[d] = xadd_dpp<0x4E>(s[d]);
        #pragma unroll
        for (int d = 0; d < 16; ++d) s[d] = xadd_sw4(s[d]);
        #pragma unroll
        for (int d = 0; d < 16; ++d) s[d] = xadd_dpp<0x128>(s[d]);

        float n2 = 0.0f;
        #pragma unroll
        for (int d = 0; d < 16; ++d) n2 = fmaf(s[d], s[d], n2);
        const float scale = n2 * __builtin_amdgcn_rcpf(1.0f + n2)
                               * __builtin_amdgcn_rsqf(n2 + CAPS_EPS);

        half2_t vpk[8];
        #pragma unroll
        for (int j = 0; j < 8; ++j)
            vpk[j] = __builtin_amdgcn_cvt_pkrtz(s[2 * j] * scale, s[2 * j + 1] * scale);
        #pragma unroll
        for (int k = 0; k < 9; ++k) {
            float dot = 0.0f;
            #pragma unroll
            for (int j = 0; j < 8; ++j)
                dot = __builtin_amdgcn_fdot2(Vp[k][j], vpk[j], dot, false);
            b_log[k] += dot;
        }
    }

    // -------- iteration 2: reduce-scatter (lane c keeps s[c]), no allgather --------
    {
        float eb[9], ebs[9];
        #pragma unroll
        for (int k = 0; k < 9; ++k) { eb[k] = __expf(b_log[k]); ebs[k] = eb[k]; }
        #pragma unroll
        for (int k = 0; k < 9; ++k) {
            ebs[k] += mov_sw_f<0x401F>(ebs[k]);
            ebs[k] += __shfl_xor(ebs[k], 32);
        }
        if ((tid & 63) < 16) {
            #pragma unroll
            for (int k = 0; k < 9; ++k) sb[1][(wv * 9 + k) * 16 + c] = ebs[k];
        }
        __syncthreads();
        float ck[9];
        #pragma unroll
        for (int k = 0; k < 9; ++k) {
            const float tot = sb[1][(0 * 9 + k) * 16 + c] + sb[1][(1 * 9 + k) * 16 + c]
                            + sb[1][(2 * 9 + k) * 16 + c] + sb[1][(3 * 9 + k) * 16 + c];
            ck[k] = eb[k] * __builtin_amdgcn_rcpf(tot);
        }

        float s[16];
        #pragma unroll
        for (int d = 0; d < 16; ++d) s[d] = 0.0f;
        #pragma unroll
        for (int k = 0; k < 9; ++k) {
            const float ckk = ck[k];
            #pragma unroll
            for (int j = 0; j < 8; ++j) {
                half2_t pk = Vp[k][j];
                s[2 * j]     = fmaf(ckk, (float)pk.x, s[2 * j]);
                s[2 * j + 1] = fmaf(ckk, (float)pk.y, s[2 * j + 1]);
            }
        }
        // recursive-halving reduce-scatter: send the half the PARTNER keeps
        const bool k8 = (c & 8) != 0;
        float t8[8];
        #pragma unroll
        for (int j = 0; j < 8; ++j) {
            const float keep = k8 ? s[j + 8] : s[j];
            const float send = k8 ? s[j] : s[j + 8];
            t8[j] = keep + mov_dpp_f<0x128>(send);
        }
        const bool k4 = (c & 4) != 0;
        float t4[4];
        #pragma unroll
        for (int j = 0; j < 4; ++j) {
            const float keep = k4 ? t8[j + 4] : t8[j];
            const float send = k4 ? t8[j] : t8[j + 4];
            t4[j] = keep + mov_sw_f<0x101F>(send);
        }
        const bool k2 = (c & 2) != 0;
        float t2[2];
        #pragma unroll
        for (int j = 0; j < 2; ++j) {
            const float keep = k2 ? t4[j + 2] : t4[j];
            const float send = k2 ? t4[j] : t4[j + 2];
            t2[j] = keep + mov_dpp_f<0x4E>(send);
        }
        const bool k1 = (c & 1) != 0;
        const float z = (k1 ? t2[1] : t2[0]) + mov_dpp_f<0xB1>(k1 ? t2[0] : t2[1]);
        // z == fully-reduced s[c] on lane c

        float n2 = z * z;                   // allreduce ||s||^2 over the 16-group
        n2 = xadd_dpp<0xB1>(n2);
        n2 = xadd_dpp<0x4E>(n2);
        n2 = xadd_sw4(n2);
        n2 = xadd_dpp<0x128>(n2);

        const float scale = n2 * __builtin_amdgcn_rcpf(1.0f + n2)
                               * __builtin_amdgcn_rsqf(n2 + CAPS_EPS);
        out[(size_t)pos * 256 + n * 16 + c] = z * scale;   // fully coalesced

        if (c == 0) {
            const float m2 = n2 * scale * scale;           // ||v||^2
            const float sc2 = m2 * __builtin_amdgcn_rcpf(1.0f + m2)
                                 * __builtin_amdgcn_rsqf(m2 + CAPS_EPS);
            out[921600 + (size_t)pos * 16 + n] = sqrtf(m2 * sc2 * sc2 + CAPS_EPS);
        }
    }
}

extern "C" void kernel_launch(void* const* d_in, const int* in_sizes, int n_in,
                              void* d_out, int out_size, void* d_ws, size_t ws_size,
                              hipStream_t stream) {
    const float* poses = (const float*)d_in[0];
    // d_in[1] = input_activations: unused by the reference computation
    const float* kern  = (const float*)d_in[2];
    float* out = (float*)d_out;
    half2_t* wpk = (half2_t*)d_ws;         // 73728 B of scratch

    pack_weights<<<dim3(144), dim3(256), 0, stream>>>(kern, wpk);
    caps_route<<<dim3(3600), dim3(256), 0, stream>>>(poses, wpk, out);
}

// Round 9
// 63.158 us; speedup vs baseline: 6.0413x; 1.2377x over previous
//
#include <hip/hip_runtime.h>

#define CAPS_EPS 1e-9f

typedef __fp16 half2_t __attribute__((ext_vector_type(2)));

__device__ __forceinline__ half2_t bc_h2(float f) {
    union { float f; half2_t h; } u; u.f = f; return u.h;
}
__device__ __forceinline__ float bc_f(half2_t h) {
    union { float f; half2_t h; } u; u.h = h; return u.f;
}

// DPP cross-lane: xor1=quad_perm(1,0,3,2)=0xB1, xor2=quad_perm(2,3,0,1)=0x4E,
// xor8=row_ror:8=0x128 (pure VALU). xor4 has no DPP row-perm on gfx9-lineage
// -> ds_swizzle bitmode 0x101F. xor16 -> ds_swizzle 0x401F.
template<int CTRL>
__device__ __forceinline__ float mov_dpp_f(float x) {
    return __builtin_bit_cast(float,
        __builtin_amdgcn_update_dpp(0, __builtin_bit_cast(int, x), CTRL, 0xF, 0xF, true));
}
template<int PAT>
__device__ __forceinline__ float mov_sw_f(float x) {
    return __builtin_bit_cast(float,
        __builtin_amdgcn_ds_swizzle(__builtin_bit_cast(int, x), PAT));
}
template<int CTRL>
__device__ __forceinline__ float xadd_dpp(float x) { return x + mov_dpp_f<CTRL>(x); }
__device__ __forceinline__ float xadd_sw4(float x) { return x + mov_sw_f<0x101F>(x); }

// ---------------------------------------------------------------------------
// Pre-pass: pack kernel weights f32 -> f16 q-pairs for v_dot2_f32_f16.
// wpk[((n*9+k)*16+c)*8 + r*2 + qh] = (W[n,k,c,2qh,r], W[n,k,c,2qh+1,r])
// ---------------------------------------------------------------------------
__global__ __launch_bounds__(256)
void pack_weights(const float* __restrict__ kern, half2_t* __restrict__ wpk) {
    const int t  = blockIdx.x * 256 + (int)threadIdx.x;   // 0..36863
    const int qh = t & 1;
    const int r  = (t >> 1) & 3;
    const int base = (t >> 3) * 16;                       // ((n*9+k)*16+c)*16
    const float f0 = kern[base + (2 * qh) * 4 + r];
    const float f1 = kern[base + (2 * qh + 1) * 4 + r];
    wpk[t] = __builtin_amdgcn_cvt_pkrtz(f0, f1);
}

// ---------------------------------------------------------------------------
// One workgroup (256 threads) per output spatial position. tid = n*16 + c.
// Votes f16-packed Vp[9][8] via v_dot2_f32_f16 (f32 accumulate); SV[16] keeps
// the f32 k-sum so iter-0's s-accumulation phase vanishes (ck==1/16 exactly).
// b-updates use unscaled S with squash scale folded into one fma per k.
// Butterflies issue the ds_swizzle (xor4) round first, then 3 pure-DPP rounds.
// Empirical: __launch_bounds__(256,2) -> VGPR cap 128 -> 4 waves/SIMD, no spill.
// ---------------------------------------------------------------------------
__global__ __launch_bounds__(256, 2)
void caps_route(const float* __restrict__ poses,    // [4][32][32][16][4][4]
                const half2_t* __restrict__ wpk,    // packed weights (pre-pass)
                float* __restrict__ out)            // poses 921600 | acts 57600
{
    const int pos = blockIdx.x;            // 0..3599
    const int b   = pos / 900;
    const int hw  = pos % 900;
    const int h   = hw / 30;
    const int w   = hw % 30;

    const int tid = (int)threadIdx.x;
    const int c   = tid & 15;              // input channel (lane-fast)
    const int n   = tid >> 4;              // output capsule

    __shared__ float4 poseH[9 * 32];       // f16 q-pairs: [k][p-half][c]
    __shared__ float  sb[2][4 * 9 * 16];   // softmax partials (buf per routing iter)

    // ---------------- stage pose blocks, cvt to f16 (coalesced) ----------------
    for (int idx = tid; idx < 288; idx += 256) {
        const int k   = idx >> 5;          // 0..8
        const int rem = idx & 31;
        const int hh  = rem >> 4;          // p-half
        const int cc  = rem & 15;
        const int ki = k / 3, kj = k % 3;
        const float4* src = reinterpret_cast<const float4*>(
            poses + (size_t)(((b * 32 + h + ki) * 32) + (w + kj)) * 256);
        const float4 t0 = src[cc * 4 + hh * 2];
        const float4 t1 = src[cc * 4 + hh * 2 + 1];
        float4 o;
        o.x = bc_f(__builtin_amdgcn_cvt_pkrtz(t0.x, t0.y));
        o.y = bc_f(__builtin_amdgcn_cvt_pkrtz(t0.z, t0.w));
        o.z = bc_f(__builtin_amdgcn_cvt_pkrtz(t1.x, t1.y));
        o.w = bc_f(__builtin_amdgcn_cvt_pkrtz(t1.z, t1.w));
        poseH[k * 32 + hh * 16 + cc] = o;
    }
    __syncthreads();

    // ------- votes via dot2 (f16 in, f32 acc) + f32 k-sum SV (iter-0 fuse) -------
    half2_t Vp[9][8];
    float SV[16];
    #pragma unroll
    for (int d = 0; d < 16; ++d) SV[d] = 0.0f;
    const half2_t* wb = wpk + (size_t)n * 1152 + c * 8;
    #pragma unroll
    for (int k = 0; k < 9; ++k) {
        const float4 t0 = poseH[k * 32 + c];
        const float4 t1 = poseH[k * 32 + 16 + c];
        const float4* gp = reinterpret_cast<const float4*>(wb + (size_t)k * 128);
        const float4 g0 = gp[0], g1 = gp[1];
        half2_t ap[4][2] = {
            {bc_h2(t0.x), bc_h2(t0.y)}, {bc_h2(t0.z), bc_h2(t0.w)},
            {bc_h2(t1.x), bc_h2(t1.y)}, {bc_h2(t1.z), bc_h2(t1.w)} };
        half2_t ga[4][2] = {
            {bc_h2(g0.x), bc_h2(g0.y)}, {bc_h2(g0.z), bc_h2(g0.w)},
            {bc_h2(g1.x), bc_h2(g1.y)}, {bc_h2(g1.z), bc_h2(g1.w)} };
        #pragma unroll
        for (int p = 0; p < 4; ++p) {
            #pragma unroll
            for (int rh = 0; rh < 2; ++rh) {
                float a0 = __builtin_amdgcn_fdot2(ap[p][0], ga[2 * rh][0], 0.0f, false);
                a0 = __builtin_amdgcn_fdot2(ap[p][1], ga[2 * rh][1], a0, false);
                float a1 = __builtin_amdgcn_fdot2(ap[p][0], ga[2 * rh + 1][0], 0.0f, false);
                a1 = __builtin_amdgcn_fdot2(ap[p][1], ga[2 * rh + 1][1], a1, false);
                const int d0 = p * 4 + 2 * rh;
                SV[d0]     += a0;
                SV[d0 + 1] += a1;
                Vp[k][p * 2 + rh] = __builtin_amdgcn_cvt_pkrtz(a0, a1);
            }
        }
    }

    float b_log[9];
    const int wv = tid >> 6;               // wave id 0..3
    const int w1 = (wv + 1) & 3, w2 = (wv + 2) & 3, w3 = (wv + 3) & 3;

    // -------- iter 0: ck == 1/16 -> butterfly directly on SV --------
    {
        float s[16];
        #pragma unroll
        for (int d = 0; d < 16; ++d) s[d] = SV[d];
        #pragma unroll
        for (int d = 0; d < 16; ++d) s[d] = xadd_sw4(s[d]);          // xor4 first
        #pragma unroll
        for (int d = 0; d < 16; ++d) s[d] = xadd_dpp<0xB1>(s[d]);
        #pragma unroll
        for (int d = 0; d < 16; ++d) s[d] = xadd_dpp<0x4E>(s[d]);
        #pragma unroll
        for (int d = 0; d < 16; ++d) s[d] = xadd_dpp<0x128>(s[d]);

        float n2S = 0.0f;
        #pragma unroll
        for (int d = 0; d < 16; ++d) n2S = fmaf(s[d], s[d], n2S);
        const float n2 = n2S * (1.0f / 256.0f);                      // ||S/16||^2
        const float g = n2 * __builtin_amdgcn_rcpf(1.0f + n2)
                           * __builtin_amdgcn_rsqf(n2 + CAPS_EPS);
        const float g16 = g * 0.0625f;                               // v0 = (S/16)*g

        half2_t spk[8];
        #pragma unroll
        for (int j = 0; j < 8; ++j)
            spk[j] = __builtin_amdgcn_cvt_pkrtz(s[2 * j], s[2 * j + 1]);
        #pragma unroll
        for (int k = 0; k < 9; ++k) {
            float dot = 0.0f;
            #pragma unroll
            for (int j = 0; j < 8; ++j)
                dot = __builtin_amdgcn_fdot2(Vp[k][j], spk[j], dot, false);
            b_log[k] = g16 * dot;
        }
    }

    // -------- iter 1: softmax + weighted accum + full allreduce --------
    {
        float eb[9], ebs[9];
        #pragma unroll
        for (int k = 0; k < 9; ++k) { eb[k] = __expf(b_log[k]); ebs[k] = eb[k]; }
        #pragma unroll
        for (int k = 0; k < 9; ++k) {
            ebs[k] += mov_sw_f<0x401F>(ebs[k]);        // xor16
            ebs[k] += __shfl_xor(ebs[k], 32);          // cross-half
        }
        if ((tid & 63) < 16) {
            #pragma unroll
            for (int k = 0; k < 9; ++k) sb[0][(wv * 9 + k) * 16 + c] = ebs[k];
        }
        __syncthreads();
        float ck[9];
        #pragma unroll
        for (int k = 0; k < 9; ++k) {
            const float tot = ebs[k] + sb[0][(w1 * 9 + k) * 16 + c]
                            + sb[0][(w2 * 9 + k) * 16 + c] + sb[0][(w3 * 9 + k) * 16 + c];
            ck[k] = eb[k] * __builtin_amdgcn_rcpf(tot);
        }

        float s[16];
        #pragma unroll
        for (int d = 0; d < 16; ++d) s[d] = 0.0f;
        #pragma unroll
        for (int k = 0; k < 9; ++k) {
            const float ckk = ck[k];
            #pragma unroll
            for (int j = 0; j < 8; ++j) {
                half2_t pk = Vp[k][j];
                s[2 * j]     = fmaf(ckk, (float)pk.x, s[2 * j]);
                s[2 * j + 1] = fmaf(ckk, (float)pk.y, s[2 * j + 1]);
            }
        }
        #pragma unroll
        for (int d = 0; d < 16; ++d) s[d] = xadd_sw4(s[d]);          // xor4 first
        #pragma unroll
        for (int d = 0; d < 16; ++d) s[d] = xadd_dpp<0xB1>(s[d]);
        #pragma unroll
        for (int d = 0; d < 16; ++d) s[d] = xadd_dpp<0x4E>(s[d]);
        #pragma unroll
        for (int d = 0; d < 16; ++d) s[d] = xadd_dpp<0x128>(s[d]);

        float n2S = 0.0f;
        #pragma unroll
        for (int d = 0; d < 16; ++d) n2S = fmaf(s[d], s[d], n2S);
        const float g = n2S * __builtin_amdgcn_rcpf(1.0f + n2S)
                            * __builtin_amdgcn_rsqf(n2S + CAPS_EPS);

        half2_t spk[8];
        #pragma unroll
        for (int j = 0; j < 8; ++j)
            spk[j] = __builtin_amdgcn_cvt_pkrtz(s[2 * j], s[2 * j + 1]);
        #pragma unroll
        for (int k = 0; k < 9; ++k) {
            float dot = 0.0f;
            #pragma unroll
            for (int j = 0; j < 8; ++j)
                dot = __builtin_amdgcn_fdot2(Vp[k][j], spk[j], dot, false);
            b_log[k] = fmaf(g, dot, b_log[k]);
        }
    }

    // -------- iter 2: reduce-scatter (lane c keeps s[c]), no allgather --------
    {
        float eb[9], ebs[9];
        #pragma unroll
        for (int k = 0; k < 9; ++k) { eb[k] = __expf(b_log[k]); ebs[k] = eb[k]; }
        #pragma unroll
        for (int k = 0; k < 9; ++k) {
            ebs[k] += mov_sw_f<0x401F>(ebs[k]);
            ebs[k] += __shfl_xor(ebs[k], 32);
        }
        if ((tid & 63) < 16) {
            #pragma unroll
            for (int k = 0; k < 9; ++k) sb[1][(wv * 9 + k) * 16 + c] = ebs[k];
        }
        __syncthreads();
        float ck[9];
        #pragma unroll
        for (int k = 0; k < 9; ++k) {
            const float tot = ebs[k] + sb[1][(w1 * 9 + k) * 16 + c]
                            + sb[1][(w2 * 9 + k) * 16 + c] + sb[1][(w3 * 9 + k) * 16 + c];
            ck[k] = eb[k] * __builtin_amdgcn_rcpf(tot);
        }

        float s[16];
        #pragma unroll
        for (int d = 0; d < 16; ++d) s[d] = 0.0f;
        #pragma unroll
        for (int k = 0; k < 9; ++k) {
            const float ckk = ck[k];
            #pragma unroll
            for (int j = 0; j < 8; ++j) {
                half2_t pk = Vp[k][j];
                s[2 * j]     = fmaf(ckk, (float)pk.x, s[2 * j]);
                s[2 * j + 1] = fmaf(ckk, (float)pk.y, s[2 * j + 1]);
            }
        }
        // recursive-halving reduce-scatter: send the half the PARTNER keeps
        const bool k8 = (c & 8) != 0;
        float t8[8];
        #pragma unroll
        for (int j = 0; j < 8; ++j) {
            const float keep = k8 ? s[j + 8] : s[j];
            const float send = k8 ? s[j] : s[j + 8];
            t8[j] = keep + mov_dpp_f<0x128>(send);
        }
        const bool k4 = (c & 4) != 0;
        float t4[4];
        #pragma unroll
        for (int j = 0; j < 4; ++j) {
            const float keep = k4 ? t8[j + 4] : t8[j];
            const float send = k4 ? t8[j] : t8[j + 4];
            t4[j] = keep + mov_sw_f<0x101F>(send);
        }
        const bool k2 = (c & 2) != 0;
        float t2[2];
        #pragma unroll
        for (int j = 0; j < 2; ++j) {
            const float keep = k2 ? t4[j + 2] : t4[j];
            const float send = k2 ? t4[j] : t4[j + 2];
            t2[j] = keep + mov_dpp_f<0x4E>(send);
        }
        const bool k1 = (c & 1) != 0;
        const float z = (k1 ? t2[1] : t2[0]) + mov_dpp_f<0xB1>(k1 ? t2[0] : t2[1]);
        // z == fully-reduced s[c] on lane c

        float n2 = z * z;                   // allreduce ||s||^2 over the 16-group
        n2 = xadd_sw4(n2);                  // xor4 first
        n2 = xadd_dpp<0xB1>(n2);
        n2 = xadd_dpp<0x4E>(n2);
        n2 = xadd_dpp<0x128>(n2);

        const float scale = n2 * __builtin_amdgcn_rcpf(1.0f + n2)
                               * __builtin_amdgcn_rsqf(n2 + CAPS_EPS);
        out[(size_t)pos * 256 + n * 16 + c] = z * scale;   // fully coalesced

        if (c == 0) {
            const float m2 = n2 * scale * scale;           // ||v||^2
            const float sc2 = m2 * __builtin_amdgcn_rcpf(1.0f + m2)
                                 * __builtin_amdgcn_rsqf(m2 + CAPS_EPS);
            out[921600 + (size_t)pos * 16 + n] = sqrtf(m2 * sc2 * sc2 + CAPS_EPS);
        }
    }
}

extern "C" void kernel_launch(void* const* d_in, const int* in_sizes, int n_in,
                              void* d_out, int out_size, void* d_ws, size_t ws_size,
                              hipStream_t stream) {
    const float* poses = (const float*)d_in[0];
    // d_in[1] = input_activations: unused by the reference computation
    const float* kern  = (const float*)d_in[2];
    float* out = (float*)d_out;
    half2_t* wpk = (half2_t*)d_ws;         // 73728 B of scratch

    pack_weights<<<dim3(144), dim3(256), 0, stream>>>(kern, wpk);
    caps_route<<<dim3(3600), dim3(256), 0, stream>>>(poses, wpk, out);
}

// Round 10
// 62.798 us; speedup vs baseline: 6.0759x; 1.0057x over previous
//
#include <hip/hip_runtime.h>

#define CAPS_EPS 1e-9f

typedef __fp16 half2_t __attribute__((ext_vector_type(2)));
typedef int int2v __attribute__((ext_vector_type(2)));

__device__ __forceinline__ half2_t bc_h2(float f) {
    union { float f; half2_t h; } u; u.f = f; return u.h;
}
__device__ __forceinline__ float bc_f(half2_t h) {
    union { float f; half2_t h; } u; u.h = h; return u.f;
}

// DPP cross-lane (pure VALU): xor1=quad_perm(1,0,3,2)=0xB1, xor2=quad_perm(2,3,0,1)=0x4E,
// row_ror:4=0x124, row_ror:8=0x128 (rotate within the 16-lane row).
// Sum-allreduce over a 16-row: xor1, xor2 (quads uniform), then +ror4 +ror8
// (accumulates all 4 quad-sums; rotation direction irrelevant for a sum).
// Exact-partner XOR exchanges that DPP can't express keep ds_swizzle:
// xor4=0x101F, xor16=0x401F.
template<int CTRL>
__device__ __forceinline__ float mov_dpp_f(float x) {
    return __builtin_bit_cast(float,
        __builtin_amdgcn_update_dpp(0, __builtin_bit_cast(int, x), CTRL, 0xF, 0xF, true));
}
template<int PAT>
__device__ __forceinline__ float mov_sw_f(float x) {
    return __builtin_bit_cast(float,
        __builtin_amdgcn_ds_swizzle(__builtin_bit_cast(int, x), PAT));
}
template<int CTRL>
__device__ __forceinline__ float xadd_dpp(float x) { return x + mov_dpp_f<CTRL>(x); }

// full 16-lane sum-allreduce, LDS-pipe-free
__device__ __forceinline__ float allred16(float x) {
    x = xadd_dpp<0xB1>(x);
    x = xadd_dpp<0x4E>(x);
    x = xadd_dpp<0x124>(x);
    x = xadd_dpp<0x128>(x);
    return x;
}

// lane[i] <-> lane[i^32] exchange: VALU permlane32_swap on gfx950, else ds_permute
__device__ __forceinline__ float xswap32(float x, int lane) {
#if __has_builtin(__builtin_amdgcn_permlane32_swap)
    const int xi = __builtin_bit_cast(int, x);
    int2v r = __builtin_amdgcn_permlane32_swap(xi, xi, false, false);
    // r[0] = {lo,lo-of-src}=... lane>=32 reads r[0] (old lo), lane<32 reads r[1] (old hi)
    return __builtin_bit_cast(float, (lane & 32) ? r[0] : r[1]);
#else
    return __shfl_xor(x, 32);
#endif
}

// ---------------------------------------------------------------------------
// Pre-pass: pack kernel weights f32 -> f16 q-pairs for v_dot2_f32_f16.
// wpk[((n*9+k)*16+c)*8 + r*2 + qh] = (W[n,k,c,2qh,r], W[n,k,c,2qh+1,r])
// ---------------------------------------------------------------------------
__global__ __launch_bounds__(256)
void pack_weights(const float* __restrict__ kern, half2_t* __restrict__ wpk) {
    const int t  = blockIdx.x * 256 + (int)threadIdx.x;   // 0..36863
    const int qh = t & 1;
    const int r  = (t >> 1) & 3;
    const int base = (t >> 3) * 16;                       // ((n*9+k)*16+c)*16
    const float f0 = kern[base + (2 * qh) * 4 + r];
    const float f1 = kern[base + (2 * qh + 1) * 4 + r];
    wpk[t] = __builtin_amdgcn_cvt_pkrtz(f0, f1);
}

// ---------------------------------------------------------------------------
// One workgroup (256 threads) per output spatial position. tid = n*16 + c.
// Votes f16-packed Vp[9][8] via v_dot2_f32_f16 (f32 accumulate); SV[16] keeps
// the f32 k-sum so iter-0's s-accumulation phase vanishes (ck==1/16 exactly).
// All sum-allreduces on pure-VALU DPP (quad_perm + row_ror); softmax cross-half
// via permlane32_swap. Empirical: __launch_bounds__(256,2) -> cap 128, no spill.
// ---------------------------------------------------------------------------
__global__ __launch_bounds__(256, 2)
void caps_route(const float* __restrict__ poses,    // [4][32][32][16][4][4]
                const half2_t* __restrict__ wpk,    // packed weights (pre-pass)
                float* __restrict__ out)            // poses 921600 | acts 57600
{
    const int pos = blockIdx.x;            // 0..3599
    const int b   = pos / 900;
    const int hw  = pos % 900;
    const int h   = hw / 30;
    const int w   = hw % 30;

    const int tid = (int)threadIdx.x;
    const int c   = tid & 15;              // input channel (lane-fast)
    const int n   = tid >> 4;              // output capsule
    const int lane = tid & 63;

    __shared__ float4 poseH[9 * 32];       // f16 q-pairs: [k][p-half][c]
    __shared__ float  sb[2][4 * 9 * 16];   // softmax partials (buf per routing iter)

    // ---------------- stage pose blocks, cvt to f16 (coalesced) ----------------
    for (int idx = tid; idx < 288; idx += 256) {
        const int k   = idx >> 5;          // 0..8
        const int rem = idx & 31;
        const int hh  = rem >> 4;          // p-half
        const int cc  = rem & 15;
        const int ki = k / 3, kj = k % 3;
        const float4* src = reinterpret_cast<const float4*>(
            poses + (size_t)(((b * 32 + h + ki) * 32) + (w + kj)) * 256);
        const float4 t0 = src[cc * 4 + hh * 2];
        const float4 t1 = src[cc * 4 + hh * 2 + 1];
        float4 o;
        o.x = bc_f(__builtin_amdgcn_cvt_pkrtz(t0.x, t0.y));
        o.y = bc_f(__builtin_amdgcn_cvt_pkrtz(t0.z, t0.w));
        o.z = bc_f(__builtin_amdgcn_cvt_pkrtz(t1.x, t1.y));
        o.w = bc_f(__builtin_amdgcn_cvt_pkrtz(t1.z, t1.w));
        poseH[k * 32 + hh * 16 + cc] = o;
    }
    __syncthreads();

    // ------- votes via dot2 (f16 in, f32 acc) + f32 k-sum SV (iter-0 fuse) -------
    half2_t Vp[9][8];
    float SV[16];
    #pragma unroll
    for (int d = 0; d < 16; ++d) SV[d] = 0.0f;
    const half2_t* wb = wpk + (size_t)n * 1152 + c * 8;
    #pragma unroll
    for (int k = 0; k < 9; ++k) {
        const float4 t0 = poseH[k * 32 + c];
        const float4 t1 = poseH[k * 32 + 16 + c];
        const float4* gp = reinterpret_cast<const float4*>(wb + (size_t)k * 128);
        const float4 g0 = gp[0], g1 = gp[1];
        half2_t ap[4][2] = {
            {bc_h2(t0.x), bc_h2(t0.y)}, {bc_h2(t0.z), bc_h2(t0.w)},
            {bc_h2(t1.x), bc_h2(t1.y)}, {bc_h2(t1.z), bc_h2(t1.w)} };
        half2_t ga[4][2] = {
            {bc_h2(g0.x), bc_h2(g0.y)}, {bc_h2(g0.z), bc_h2(g0.w)},
            {bc_h2(g1.x), bc_h2(g1.y)}, {bc_h2(g1.z), bc_h2(g1.w)} };
        #pragma unroll
        for (int p = 0; p < 4; ++p) {
            #pragma unroll
            for (int rh = 0; rh < 2; ++rh) {
                float a0 = __builtin_amdgcn_fdot2(ap[p][0], ga[2 * rh][0], 0.0f, false);
                a0 = __builtin_amdgcn_fdot2(ap[p][1], ga[2 * rh][1], a0, false);
                float a1 = __builtin_amdgcn_fdot2(ap[p][0], ga[2 * rh + 1][0], 0.0f, false);
                a1 = __builtin_amdgcn_fdot2(ap[p][1], ga[2 * rh + 1][1], a1, false);
                const int d0 = p * 4 + 2 * rh;
                SV[d0]     += a0;
                SV[d0 + 1] += a1;
                Vp[k][p * 2 + rh] = __builtin_amdgcn_cvt_pkrtz(a0, a1);
            }
        }
    }

    float b_log[9];
    const int wv = tid >> 6;               // wave id 0..3
    const int w1 = (wv + 1) & 3, w2 = (wv + 2) & 3, w3 = (wv + 3) & 3;

    // -------- iter 0: ck == 1/16 -> allreduce directly on SV --------
    {
        float s[16];
        #pragma unroll
        for (int d = 0; d < 16; ++d) s[d] = allred16(SV[d]);

        float n2S = 0.0f;
        #pragma unroll
        for (int d = 0; d < 16; ++d) n2S = fmaf(s[d], s[d], n2S);
        const float n2 = n2S * (1.0f / 256.0f);                      // ||S/16||^2
        const float g = n2 * __builtin_amdgcn_rcpf(1.0f + n2)
                           * __builtin_amdgcn_rsqf(n2 + CAPS_EPS);
        const float g16 = g * 0.0625f;                               // v0 = (S/16)*g

        half2_t spk[8];
        #pragma unroll
        for (int j = 0; j < 8; ++j)
            spk[j] = __builtin_amdgcn_cvt_pkrtz(s[2 * j], s[2 * j + 1]);
        #pragma unroll
        for (int k = 0; k < 9; ++k) {
            float dot = 0.0f;
            #pragma unroll
            for (int j = 0; j < 8; ++j)
                dot = __builtin_amdgcn_fdot2(Vp[k][j], spk[j], dot, false);
            b_log[k] = g16 * dot;
        }
    }

    // -------- iter 1: softmax + weighted accum + full allreduce --------
    {
        float eb[9], ebs[9];
        #pragma unroll
        for (int k = 0; k < 9; ++k) { eb[k] = __expf(b_log[k]); ebs[k] = eb[k]; }
        #pragma unroll
        for (int k = 0; k < 9; ++k) {
            ebs[k] += mov_sw_f<0x401F>(ebs[k]);        // xor16 (LDS swizzle)
            ebs[k] += xswap32(ebs[k], lane);           // cross-half (VALU permlane)
        }
        if (lane < 16) {
            #pragma unroll
            for (int k = 0; k < 9; ++k) sb[0][(wv * 9 + k) * 16 + c] = ebs[k];
        }
        __syncthreads();
        float ck[9];
        #pragma unroll
        for (int k = 0; k < 9; ++k) {
            const float tot = ebs[k] + sb[0][(w1 * 9 + k) * 16 + c]
                            + sb[0][(w2 * 9 + k) * 16 + c] + sb[0][(w3 * 9 + k) * 16 + c];
            ck[k] = eb[k] * __builtin_amdgcn_rcpf(tot);
        }

        float s[16];
        #pragma unroll
        for (int d = 0; d < 16; ++d) s[d] = 0.0f;
        #pragma unroll
        for (int k = 0; k < 9; ++k) {
            const float ckk = ck[k];
            #pragma unroll
            for (int j = 0; j < 8; ++j) {
                half2_t pk = Vp[k][j];
                s[2 * j]     = fmaf(ckk, (float)pk.x, s[2 * j]);
                s[2 * j + 1] = fmaf(ckk, (float)pk.y, s[2 * j + 1]);
            }
        }
        #pragma unroll
        for (int d = 0; d < 16; ++d) s[d] = allred16(s[d]);

        float n2S = 0.0f;
        #pragma unroll
        for (int d = 0; d < 16; ++d) n2S = fmaf(s[d], s[d], n2S);
        const float g = n2S * __builtin_amdgcn_rcpf(1.0f + n2S)
                            * __builtin_amdgcn_rsqf(n2S + CAPS_EPS);

        half2_t spk[8];
        #pragma unroll
        for (int j = 0; j < 8; ++j)
            spk[j] = __builtin_amdgcn_cvt_pkrtz(s[2 * j], s[2 * j + 1]);
        #pragma unroll
        for (int k = 0; k < 9; ++k) {
            float dot = 0.0f;
            #pragma unroll
            for (int j = 0; j < 8; ++j)
                dot = __builtin_amdgcn_fdot2(Vp[k][j], spk[j], dot, false);
            b_log[k] = fmaf(g, dot, b_log[k]);
        }
    }

    // -------- iter 2: reduce-scatter (lane c keeps s[c]), no allgather --------
    {
        float eb[9], ebs[9];
        #pragma unroll
        for (int k = 0; k < 9; ++k) { eb[k] = __expf(b_log[k]); ebs[k] = eb[k]; }
        #pragma unroll
        for (int k = 0; k < 9; ++k) {
            ebs[k] += mov_sw_f<0x401F>(ebs[k]);
            ebs[k] += xswap32(ebs[k], lane);
        }
        if (lane < 16) {
            #pragma unroll
            for (int k = 0; k < 9; ++k) sb[1][(wv * 9 + k) * 16 + c] = ebs[k];
        }
        __syncthreads();
        float ck[9];
        #pragma unroll
        for (int k = 0; k < 9; ++k) {
            const float tot = ebs[k] + sb[1][(w1 * 9 + k) * 16 + c]
                            + sb[1][(w2 * 9 + k) * 16 + c] + sb[1][(w3 * 9 + k) * 16 + c];
            ck[k] = eb[k] * __builtin_amdgcn_rcpf(tot);
        }

        float s[16];
        #pragma unroll
        for (int d = 0; d < 16; ++d) s[d] = 0.0f;
        #pragma unroll
        for (int k = 0; k < 9; ++k) {
            const float ckk = ck[k];
            #pragma unroll
            for (int j = 0; j < 8; ++j) {
                half2_t pk = Vp[k][j];
                s[2 * j]     = fmaf(ckk, (float)pk.x, s[2 * j]);
                s[2 * j + 1] = fmaf(ckk, (float)pk.y, s[2 * j + 1]);
            }
        }
        // recursive-halving reduce-scatter: send the half the PARTNER keeps
        const bool k8 = (c & 8) != 0;
        float t8[8];
        #pragma unroll
        for (int j = 0; j < 8; ++j) {
            const float keep = k8 ? s[j + 8] : s[j];
            const float send = k8 ? s[j] : s[j + 8];
            t8[j] = keep + mov_dpp_f<0x128>(send);     // ror8 == xor8 within 16
        }
        const bool k4 = (c & 4) != 0;
        float t4[4];
        #pragma unroll
        for (int j = 0; j < 4; ++j) {
            const float keep = k4 ? t8[j + 4] : t8[j];
            const float send = k4 ? t8[j] : t8[j + 4];
            t4[j] = keep + mov_sw_f<0x101F>(send);     // exact xor4 (swizzle)
        }
        const bool k2 = (c & 2) != 0;
        float t2[2];
        #pragma unroll
        for (int j = 0; j < 2; ++j) {
            const float keep = k2 ? t4[j + 2] : t4[j];
            const float send = k2 ? t4[j] : t4[j + 2];
            t2[j] = keep + mov_dpp_f<0x4E>(send);
        }
        const bool k1 = (c & 1) != 0;
        const float z = (k1 ? t2[1] : t2[0]) + mov_dpp_f<0xB1>(k1 ? t2[0] : t2[1]);
        // z == fully-reduced s[c] on lane c

        const float n2 = allred16(z * z);              // ||s||^2 over the 16-group

        const float scale = n2 * __builtin_amdgcn_rcpf(1.0f + n2)
                               * __builtin_amdgcn_rsqf(n2 + CAPS_EPS);
        out[(size_t)pos * 256 + n * 16 + c] = z * scale;   // fully coalesced

        if (c == 0) {
            const float m2 = n2 * scale * scale;           // ||v||^2
            const float sc2 = m2 * __builtin_amdgcn_rcpf(1.0f + m2)
                                 * __builtin_amdgcn_rsqf(m2 + CAPS_EPS);
            out[921600 + (size_t)pos * 16 + n] = sqrtf(m2 * sc2 * sc2 + CAPS_EPS);
        }
    }
}

extern "C" void kernel_launch(void* const* d_in, const int* in_sizes, int n_in,
                              void* d_out, int out_size, void* d_ws, size_t ws_size,
                              hipStream_t stream) {
    const float* poses = (const float*)d_in[0];
    // d_in[1] = input_activations: unused by the reference computation
    const float* kern  = (const float*)d_in[2];
    float* out = (float*)d_out;
    half2_t* wpk = (half2_t*)d_ws;         // 73728 B of scratch

    pack_weights<<<dim3(144), dim3(256), 0, stream>>>(kern, wpk);
    caps_route<<<dim3(3600), dim3(256), 0, stream>>>(poses, wpk, out);
}

// Round 11
// 61.179 us; speedup vs baseline: 6.2367x; 1.0265x over previous
//
#include <hip/hip_runtime.h>

#define CAPS_EPS 1e-9f

typedef __fp16 half2_t __attribute__((ext_vector_type(2)));
typedef int int2v __attribute__((ext_vector_type(2)));

#if __has_builtin(__builtin_amdgcn_exp2f)
#define EXP2(x) __builtin_amdgcn_exp2f(x)
#else
#define EXP2(x) exp2f(x)
#endif
#define LOG2E 1.44269504f

__device__ __forceinline__ half2_t bc_h2(float f) {
    union { float f; half2_t h; } u; u.f = f; return u.h;
}
__device__ __forceinline__ float bc_f(half2_t h) {
    union { float f; half2_t h; } u; u.h = h; return u.f;
}

// DPP cross-lane (pure VALU): xor1=quad_perm(1,0,3,2)=0xB1, xor2=quad_perm(2,3,0,1)=0x4E,
// row_ror:4=0x124, row_ror:8=0x128. Sum-allreduce over 16 lanes: xor1,xor2 then
// ror4+ror8 (rotation direction irrelevant for a sum). Exact-partner XOR that DPP
// can't express keeps ds_swizzle: xor4=0x101F, xor16=0x401F.
template<int CTRL>
__device__ __forceinline__ float mov_dpp_f(float x) {
    return __builtin_bit_cast(float,
        __builtin_amdgcn_update_dpp(0, __builtin_bit_cast(int, x), CTRL, 0xF, 0xF, true));
}
template<int PAT>
__device__ __forceinline__ float mov_sw_f(float x) {
    return __builtin_bit_cast(float,
        __builtin_amdgcn_ds_swizzle(__builtin_bit_cast(int, x), PAT));
}
template<int CTRL>
__device__ __forceinline__ float xadd_dpp(float x) { return x + mov_dpp_f<CTRL>(x); }

// full 16-lane sum-allreduce, LDS-pipe-free
__device__ __forceinline__ float allred16(float x) {
    x = xadd_dpp<0xB1>(x);
    x = xadd_dpp<0x4E>(x);
    x = xadd_dpp<0x124>(x);
    x = xadd_dpp<0x128>(x);
    return x;
}

// lane[i] <-> lane[i^32] exchange: VALU permlane32_swap on gfx950
__device__ __forceinline__ float xswap32(float x, int lane) {
#if __has_builtin(__builtin_amdgcn_permlane32_swap)
    const int xi = __builtin_bit_cast(int, x);
    int2v r = __builtin_amdgcn_permlane32_swap(xi, xi, false, false);
    return __builtin_bit_cast(float, (lane & 32) ? r[0] : r[1]);
#else
    return __shfl_xor(x, 32);
#endif
}

// tree sum-of-squares of 16 floats: depth ~6 instead of 16
__device__ __forceinline__ float sumsq16(const float* s) {
    float a0 = 0.0f, a1 = 0.0f, a2 = 0.0f, a3 = 0.0f;
    #pragma unroll
    for (int d = 0; d < 16; d += 4) {
        a0 = fmaf(s[d],     s[d],     a0);
        a1 = fmaf(s[d + 1], s[d + 1], a1);
        a2 = fmaf(s[d + 2], s[d + 2], a2);
        a3 = fmaf(s[d + 3], s[d + 3], a3);
    }
    return (a0 + a1) + (a2 + a3);
}

// ---------------------------------------------------------------------------
// Pre-pass: pack kernel weights f32 -> f16 q-pairs for v_dot2_f32_f16.
// wpk[((n*9+k)*16+c)*8 + r*2 + qh] = (W[n,k,c,2qh,r], W[n,k,c,2qh+1,r])
// ---------------------------------------------------------------------------
__global__ __launch_bounds__(256)
void pack_weights(const float* __restrict__ kern, half2_t* __restrict__ wpk) {
    const int t  = blockIdx.x * 256 + (int)threadIdx.x;   // 0..36863
    const int qh = t & 1;
    const int r  = (t >> 1) & 3;
    const int base = (t >> 3) * 16;                       // ((n*9+k)*16+c)*16
    const float f0 = kern[base + (2 * qh) * 4 + r];
    const float f1 = kern[base + (2 * qh + 1) * 4 + r];
    wpk[t] = __builtin_amdgcn_cvt_pkrtz(f0, f1);
}

// ---------------------------------------------------------------------------
// One workgroup (256 threads) per output spatial position. tid = n*16 + c.
// Votes f16-packed Vp[9][8] via v_dot2_f32_f16 (f32 accumulate); SV[16] f32
// k-sum makes iter-0's s-accum free. Weight loads software-pipelined one k
// ahead (L2 latency hides under the previous k's VALU). Softmax partials in
// LDS as [k][c][wave] float4 (one b128 read per k). Logits kept in log2
// domain (single v_exp). All allreduces pure-VALU DPP.
// Empirical: __launch_bounds__(256,2) -> VGPR cap 128 -> no spill at ~92-115.
// ---------------------------------------------------------------------------
__global__ __launch_bounds__(256, 2)
void caps_route(const float* __restrict__ poses,    // [4][32][32][16][4][4]
                const half2_t* __restrict__ wpk,    // packed weights (pre-pass)
                float* __restrict__ out)            // poses 921600 | acts 57600
{
    const int pos = blockIdx.x;            // 0..3599
    const int b   = pos / 900;
    const int hw  = pos % 900;
    const int h   = hw / 30;
    const int w   = hw % 30;

    const int tid = (int)threadIdx.x;
    const int c   = tid & 15;              // input channel (lane-fast)
    const int n   = tid >> 4;              // output capsule
    const int lane = tid & 63;

    __shared__ float4 poseH[9 * 32];       // f16 q-pairs: [k][p-half][c]
    __shared__ float4 sbv[2][9 * 16];      // softmax partials [k][c] = {w0,w1,w2,w3}

    // weight pointer + prefetch k=0 BEFORE staging (hides under pose loads)
    const float4* gf4 = reinterpret_cast<const float4*>(wpk + (size_t)n * 1152 + c * 8);
    float4 gA = gf4[0], gB = gf4[1];

    // ---------------- stage pose blocks, cvt to f16 (coalesced) ----------------
    for (int idx = tid; idx < 288; idx += 256) {
        const int k   = idx >> 5;          // 0..8
        const int rem = idx & 31;
        const int hh  = rem >> 4;          // p-half
        const int cc  = rem & 15;
        const int ki = k / 3, kj = k % 3;
        const float4* src = reinterpret_cast<const float4*>(
            poses + (size_t)(((b * 32 + h + ki) * 32) + (w + kj)) * 256);
        const float4 t0 = src[cc * 4 + hh * 2];
        const float4 t1 = src[cc * 4 + hh * 2 + 1];
        float4 o;
        o.x = bc_f(__builtin_amdgcn_cvt_pkrtz(t0.x, t0.y));
        o.y = bc_f(__builtin_amdgcn_cvt_pkrtz(t0.z, t0.w));
        o.z = bc_f(__builtin_amdgcn_cvt_pkrtz(t1.x, t1.y));
        o.w = bc_f(__builtin_amdgcn_cvt_pkrtz(t1.z, t1.w));
        poseH[k * 32 + hh * 16 + cc] = o;
    }
    __syncthreads();

    // ------- votes via dot2 (f16 in, f32 acc) + f32 k-sum SV (iter-0 fuse) -------
    half2_t Vp[9][8];
    float SV[16];
    #pragma unroll
    for (int d = 0; d < 16; ++d) SV[d] = 0.0f;
    #pragma unroll
    for (int k = 0; k < 9; ++k) {
        const float4 g0 = gA, g1 = gB;
        if (k < 8) { gA = gf4[(k + 1) * 32]; gB = gf4[(k + 1) * 32 + 1]; }  // prefetch k+1
        const float4 t0 = poseH[k * 32 + c];
        const float4 t1 = poseH[k * 32 + 16 + c];
        half2_t ap[4][2] = {
            {bc_h2(t0.x), bc_h2(t0.y)}, {bc_h2(t0.z), bc_h2(t0.w)},
            {bc_h2(t1.x), bc_h2(t1.y)}, {bc_h2(t1.z), bc_h2(t1.w)} };
        half2_t ga[4][2] = {
            {bc_h2(g0.x), bc_h2(g0.y)}, {bc_h2(g0.z), bc_h2(g0.w)},
            {bc_h2(g1.x), bc_h2(g1.y)}, {bc_h2(g1.z), bc_h2(g1.w)} };
        #pragma unroll
        for (int p = 0; p < 4; ++p) {
            #pragma unroll
            for (int rh = 0; rh < 2; ++rh) {
                float a0 = __builtin_amdgcn_fdot2(ap[p][0], ga[2 * rh][0], 0.0f, false);
                a0 = __builtin_amdgcn_fdot2(ap[p][1], ga[2 * rh][1], a0, false);
                float a1 = __builtin_amdgcn_fdot2(ap[p][0], ga[2 * rh + 1][0], 0.0f, false);
                a1 = __builtin_amdgcn_fdot2(ap[p][1], ga[2 * rh + 1][1], a1, false);
                const int d0 = p * 4 + 2 * rh;
                SV[d0]     += a0;
                SV[d0 + 1] += a1;
                Vp[k][p * 2 + rh] = __builtin_amdgcn_cvt_pkrtz(a0, a1);
            }
        }
    }

    float b_log[9];                        // logits in log2 domain
    const int wv = tid >> 6;               // wave id 0..3

    // -------- iter 0: ck == 1/16 -> allreduce directly on SV --------
    {
        float s[16];
        #pragma unroll
        for (int d = 0; d < 16; ++d) s[d] = allred16(SV[d]);

        const float n2 = sumsq16(s) * (1.0f / 256.0f);               // ||S/16||^2
        const float g = n2 * __builtin_amdgcn_rcpf(1.0f + n2)
                           * __builtin_amdgcn_rsqf(n2 + CAPS_EPS);
        const float gl2 = g * (0.0625f * LOG2E);                     // log2-domain

        half2_t spk[8];
        #pragma unroll
        for (int j = 0; j < 8; ++j)
            spk[j] = __builtin_amdgcn_cvt_pkrtz(s[2 * j], s[2 * j + 1]);
        #pragma unroll
        for (int k = 0; k < 9; ++k) {
            float dot = 0.0f;
            #pragma unroll
            for (int j = 0; j < 8; ++j)
                dot = __builtin_amdgcn_fdot2(Vp[k][j], spk[j], dot, false);
            b_log[k] = gl2 * dot;
        }
    }

    // -------- iter 1: softmax + weighted accum + full allreduce --------
    {
        float eb[9], ebs[9];
        #pragma unroll
        for (int k = 0; k < 9; ++k) { eb[k] = EXP2(b_log[k]); ebs[k] = eb[k]; }
        #pragma unroll
        for (int k = 0; k < 9; ++k) {
            ebs[k] += mov_sw_f<0x401F>(ebs[k]);        // xor16 (LDS swizzle)
            ebs[k] += xswap32(ebs[k], lane);           // cross-half (VALU permlane)
        }
        if (lane < 16) {
            #pragma unroll
            for (int k = 0; k < 9; ++k)
                reinterpret_cast<float*>(&sbv[0][k * 16 + c])[wv] = ebs[k];
        }
        __syncthreads();
        float ck[9];
        #pragma unroll
        for (int k = 0; k < 9; ++k) {
            const float4 t = sbv[0][k * 16 + c];
            const float tot = (t.x + t.y) + (t.z + t.w);
            ck[k] = eb[k] * __builtin_amdgcn_rcpf(tot);
        }

        float s[16];
        #pragma unroll
        for (int d = 0; d < 16; ++d) s[d] = 0.0f;
        #pragma unroll
        for (int k = 0; k < 9; ++k) {
            const float ckk = ck[k];
            #pragma unroll
            for (int j = 0; j < 8; ++j) {
                half2_t pk = Vp[k][j];
                s[2 * j]     = fmaf(ckk, (float)pk.x, s[2 * j]);
                s[2 * j + 1] = fmaf(ckk, (float)pk.y, s[2 * j + 1]);
            }
        }
        #pragma unroll
        for (int d = 0; d < 16; ++d) s[d] = allred16(s[d]);

        const float n2S = sumsq16(s);
        const float g = n2S * __builtin_amdgcn_rcpf(1.0f + n2S)
                            * __builtin_amdgcn_rsqf(n2S + CAPS_EPS);
        const float gl2 = g * LOG2E;

        half2_t spk[8];
        #pragma unroll
        for (int j = 0; j < 8; ++j)
            spk[j] = __builtin_amdgcn_cvt_pkrtz(s[2 * j], s[2 * j + 1]);
        #pragma unroll
        for (int k = 0; k < 9; ++k) {
            float dot = 0.0f;
            #pragma unroll
            for (int j = 0; j < 8; ++j)
                dot = __builtin_amdgcn_fdot2(Vp[k][j], spk[j], dot, false);
            b_log[k] = fmaf(gl2, dot, b_log[k]);
        }
    }

    // -------- iter 2: reduce-scatter (lane c keeps s[c]), no allgather --------
    {
        float eb[9], ebs[9];
        #pragma unroll
        for (int k = 0; k < 9; ++k) { eb[k] = EXP2(b_log[k]); ebs[k] = eb[k]; }
        #pragma unroll
        for (int k = 0; k < 9; ++k) {
            ebs[k] += mov_sw_f<0x401F>(ebs[k]);
            ebs[k] += xswap32(ebs[k], lane);
        }
        if (lane < 16) {
            #pragma unroll
            for (int k = 0; k < 9; ++k)
                reinterpret_cast<float*>(&sbv[1][k * 16 + c])[wv] = ebs[k];
        }
        __syncthreads();
        float ck[9];
        #pragma unroll
        for (int k = 0; k < 9; ++k) {
            const float4 t = sbv[1][k * 16 + c];
            const float tot = (t.x + t.y) + (t.z + t.w);
            ck[k] = eb[k] * __builtin_amdgcn_rcpf(tot);
        }

        float s[16];
        #pragma unroll
        for (int d = 0; d < 16; ++d) s[d] = 0.0f;
        #pragma unroll
        for (int k = 0; k < 9; ++k) {
            const float ckk = ck[k];
            #pragma unroll
            for (int j = 0; j < 8; ++j) {
                half2_t pk = Vp[k][j];
                s[2 * j]     = fmaf(ckk, (float)pk.x, s[2 * j]);
                s[2 * j + 1] = fmaf(ckk, (float)pk.y, s[2 * j + 1]);
            }
        }
        // recursive-halving reduce-scatter: send the half the PARTNER keeps
        const bool k8 = (c & 8) != 0;
        float t8[8];
        #pragma unroll
        for (int j = 0; j < 8; ++j) {
            const float keep = k8 ? s[j + 8] : s[j];
            const float send = k8 ? s[j] : s[j + 8];
            t8[j] = keep + mov_dpp_f<0x128>(send);     // ror8 == xor8 within 16
        }
        const bool k4 = (c & 4) != 0;
        float t4[4];
        #pragma unroll
        for (int j = 0; j < 4; ++j) {
            const float keep = k4 ? t8[j + 4] : t8[j];
            const float send = k4 ? t8[j] : t8[j + 4];
            t4[j] = keep + mov_sw_f<0x101F>(send);     // exact xor4 (swizzle)
        }
        const bool k2 = (c & 2) != 0;
        float t2[2];
        #pragma unroll
        for (int j = 0; j < 2; ++j) {
            const float keep = k2 ? t4[j + 2] : t4[j];
            const float send = k2 ? t4[j] : t4[j + 2];
            t2[j] = keep + mov_dpp_f<0x4E>(send);
        }
        const bool k1 = (c & 1) != 0;
        const float z = (k1 ? t2[1] : t2[0]) + mov_dpp_f<0xB1>(k1 ? t2[0] : t2[1]);
        // z == fully-reduced s[c] on lane c

        const float n2 = allred16(z * z);              // ||s||^2 over the 16-group

        const float scale = n2 * __builtin_amdgcn_rcpf(1.0f + n2)
                               * __builtin_amdgcn_rsqf(n2 + CAPS_EPS);
        out[(size_t)pos * 256 + n * 16 + c] = z * scale;   // fully coalesced

        if (c == 0) {
            const float m2 = n2 * scale * scale;           // ||v||^2
            const float sc2 = m2 * __builtin_amdgcn_rcpf(1.0f + m2)
                                 * __builtin_amdgcn_rsqf(m2 + CAPS_EPS);
            out[921600 + (size_t)pos * 16 + n] = sqrtf(m2 * sc2 * sc2 + CAPS_EPS);
        }
    }
}

extern "C" void kernel_launch(void* const* d_in, const int* in_sizes, int n_in,
                              void* d_out, int out_size, void* d_ws, size_t ws_size,
                              hipStream_t stream) {
    const float* poses = (const float*)d_in[0];
    // d_in[1] = input_activations: unused by the reference computation
    const float* kern  = (const float*)d_in[2];
    float* out = (float*)d_out;
    half2_t* wpk = (half2_t*)d_ws;         // 73728 B of scratch

    pack_weights<<<dim3(144), dim3(256), 0, stream>>>(kern, wpk);
    caps_route<<<dim3(3600), dim3(256), 0, stream>>>(poses, wpk, out);
}

// Round 12
// 56.268 us; speedup vs baseline: 6.7810x; 1.0873x over previous
//
#include <hip/hip_runtime.h>

#define CAPS_EPS 1e-9f

typedef __fp16 half2_t __attribute__((ext_vector_type(2)));
typedef int int2v __attribute__((ext_vector_type(2)));

#if __has_builtin(__builtin_amdgcn_exp2f)
#define EXP2(x) __builtin_amdgcn_exp2f(x)
#else
#define EXP2(x) exp2f(x)
#endif
#define LOG2E 1.44269504f

__device__ __forceinline__ half2_t bc_h2(float f) {
    union { float f; half2_t h; } u; u.f = f; return u.h;
}
__device__ __forceinline__ float bc_f(half2_t h) {
    union { float f; half2_t h; } u; u.h = h; return u.f;
}

// DPP cross-lane (pure VALU): xor1=quad_perm(1,0,3,2)=0xB1, xor2=quad_perm(2,3,0,1)=0x4E,
// row_ror:4=0x124, row_ror:8=0x128. Sum-allreduce over 16 lanes: xor1,xor2 then
// ror4+ror8 (rotation direction irrelevant for a sum). Exact-partner xor4 that DPP
// can't express keeps ds_swizzle 0x101F.
template<int CTRL>
__device__ __forceinline__ float mov_dpp_f(float x) {
    return __builtin_bit_cast(float,
        __builtin_amdgcn_update_dpp(0, __builtin_bit_cast(int, x), CTRL, 0xF, 0xF, true));
}
template<int PAT>
__device__ __forceinline__ float mov_sw_f(float x) {
    return __builtin_bit_cast(float,
        __builtin_amdgcn_ds_swizzle(__builtin_bit_cast(int, x), PAT));
}
template<int CTRL>
__device__ __forceinline__ float xadd_dpp(float x) { return x + mov_dpp_f<CTRL>(x); }

// full 16-lane sum-allreduce, LDS-pipe-free
__device__ __forceinline__ float allred16(float x) {
    x = xadd_dpp<0xB1>(x);
    x = xadd_dpp<0x4E>(x);
    x = xadd_dpp<0x124>(x);
    x = xadd_dpp<0x128>(x);
    return x;
}

// lane[i] <-> lane[i^32]: VALU permlane32_swap on gfx950
__device__ __forceinline__ float xswap32(float x, int lane) {
#if __has_builtin(__builtin_amdgcn_permlane32_swap)
    const int xi = __builtin_bit_cast(int, x);
    int2v r = __builtin_amdgcn_permlane32_swap(xi, xi, false, false);
    return __builtin_bit_cast(float, (lane & 32) ? r[0] : r[1]);
#else
    return __shfl_xor(x, 32);
#endif
}

// lane[i] <-> lane[i^16]: VALU permlane16_swap on gfx950, else ds_swizzle xor16
__device__ __forceinline__ float xswap16(float x, int lane) {
#if __has_builtin(__builtin_amdgcn_permlane16_swap)
    const int xi = __builtin_bit_cast(int, x);
    int2v r = __builtin_amdgcn_permlane16_swap(xi, xi, false, false);
    return __builtin_bit_cast(float, (lane & 16) ? r[0] : r[1]);
#else
    return mov_sw_f<0x401F>(x);
#endif
}

// s += ck * f16(lo/hi of pk)  -- forced v_fma_mix_f32 (1 op, no separate cvt)
__device__ __forceinline__ void fmamix_lo(float& acc, float c, half2_t pk) {
    const int pi = __builtin_bit_cast(int, pk);
    asm("v_fma_mix_f32 %0, %1, %2, %0 op_sel_hi:[0,1,0]"
        : "+v"(acc) : "v"(c), "v"(pi));
}
__device__ __forceinline__ void fmamix_hi(float& acc, float c, half2_t pk) {
    const int pi = __builtin_bit_cast(int, pk);
    asm("v_fma_mix_f32 %0, %1, %2, %0 op_sel:[0,1,0] op_sel_hi:[0,1,0]"
        : "+v"(acc) : "v"(c), "v"(pi));
}

// tree sum-of-squares of 16 floats: depth ~6 instead of 16
__device__ __forceinline__ float sumsq16(const float* s) {
    float a0 = 0.0f, a1 = 0.0f, a2 = 0.0f, a3 = 0.0f;
    #pragma unroll
    for (int d = 0; d < 16; d += 4) {
        a0 = fmaf(s[d],     s[d],     a0);
        a1 = fmaf(s[d + 1], s[d + 1], a1);
        a2 = fmaf(s[d + 2], s[d + 2], a2);
        a3 = fmaf(s[d + 3], s[d + 3], a3);
    }
    return (a0 + a1) + (a2 + a3);
}

// ---------------------------------------------------------------------------
// Pre-pass: pack kernel weights f32 -> f16 q-pairs for v_dot2_f32_f16.
// wpk[((n*9+k)*16+c)*8 + r*2 + qh] = (W[n,k,c,2qh,r], W[n,k,c,2qh+1,r])
// ---------------------------------------------------------------------------
__global__ __launch_bounds__(256)
void pack_weights(const float* __restrict__ kern, half2_t* __restrict__ wpk) {
    const int t  = blockIdx.x * 256 + (int)threadIdx.x;   // 0..36863
    const int qh = t & 1;
    const int r  = (t >> 1) & 3;
    const int base = (t >> 3) * 16;                       // ((n*9+k)*16+c)*16
    const float f0 = kern[base + (2 * qh) * 4 + r];
    const float f1 = kern[base + (2 * qh + 1) * 4 + r];
    wpk[t] = __builtin_amdgcn_cvt_pkrtz(f0, f1);
}

// ---------------------------------------------------------------------------
// One workgroup (256 threads) per output spatial position. tid = n*16 + c.
// Votes f16-packed Vp[9][8] via v_dot2_f32_f16 (f32 accumulate); SV[16] f32
// k-sum makes iter-0's s-accum free. Weight loads software-pipelined one k
// ahead. s-accum phases use forced v_fma_mix_f32 (f16 operand, f32 accum,
// 1 op/element). Softmax cross-lane on permlane16/32_swap (pure VALU).
// Empirical: __launch_bounds__(256,2) -> VGPR cap 128 -> no spill at ~100.
// ---------------------------------------------------------------------------
__global__ __launch_bounds__(256, 2)
void caps_route(const float* __restrict__ poses,    // [4][32][32][16][4][4]
                const half2_t* __restrict__ wpk,    // packed weights (pre-pass)
                float* __restrict__ out)            // poses 921600 | acts 57600
{
    const int pos = blockIdx.x;            // 0..3599
    const int b   = pos / 900;
    const int hw  = pos % 900;
    const int h   = hw / 30;
    const int w   = hw % 30;

    const int tid = (int)threadIdx.x;
    const int c   = tid & 15;              // input channel (lane-fast)
    const int n   = tid >> 4;              // output capsule
    const int lane = tid & 63;

    __shared__ float4 poseH[9 * 32];       // f16 q-pairs: [k][p-half][c]
    __shared__ float4 sbv[2][9 * 16];      // softmax partials [k][c] = {w0,w1,w2,w3}

    // weight pointer + prefetch k=0 BEFORE staging (hides under pose loads)
    const float4* gf4 = reinterpret_cast<const float4*>(wpk + (size_t)n * 1152 + c * 8);
    float4 gA = gf4[0], gB = gf4[1];

    // ---------------- stage pose blocks, cvt to f16 (coalesced) ----------------
    for (int idx = tid; idx < 288; idx += 256) {
        const int k   = idx >> 5;          // 0..8
        const int rem = idx & 31;
        const int hh  = rem >> 4;          // p-half
        const int cc  = rem & 15;
        const int ki = k / 3, kj = k % 3;
        const float4* src = reinterpret_cast<const float4*>(
            poses + (size_t)(((b * 32 + h + ki) * 32) + (w + kj)) * 256);
        const float4 t0 = src[cc * 4 + hh * 2];
        const float4 t1 = src[cc * 4 + hh * 2 + 1];
        float4 o;
        o.x = bc_f(__builtin_amdgcn_cvt_pkrtz(t0.x, t0.y));
        o.y = bc_f(__builtin_amdgcn_cvt_pkrtz(t0.z, t0.w));
        o.z = bc_f(__builtin_amdgcn_cvt_pkrtz(t1.x, t1.y));
        o.w = bc_f(__builtin_amdgcn_cvt_pkrtz(t1.z, t1.w));
        poseH[k * 32 + hh * 16 + cc] = o;
    }
    __syncthreads();

    // ------- votes via dot2 (f16 in, f32 acc) + f32 k-sum SV (iter-0 fuse) -------
    half2_t Vp[9][8];
    float SV[16];
    #pragma unroll
    for (int d = 0; d < 16; ++d) SV[d] = 0.0f;
    #pragma unroll
    for (int k = 0; k < 9; ++k) {
        const float4 g0 = gA, g1 = gB;
        if (k < 8) { gA = gf4[(k + 1) * 32]; gB = gf4[(k + 1) * 32 + 1]; }  // prefetch k+1
        const float4 t0 = poseH[k * 32 + c];
        const float4 t1 = poseH[k * 32 + 16 + c];
        half2_t ap[4][2] = {
            {bc_h2(t0.x), bc_h2(t0.y)}, {bc_h2(t0.z), bc_h2(t0.w)},
            {bc_h2(t1.x), bc_h2(t1.y)}, {bc_h2(t1.z), bc_h2(t1.w)} };
        half2_t ga[4][2] = {
            {bc_h2(g0.x), bc_h2(g0.y)}, {bc_h2(g0.z), bc_h2(g0.w)},
            {bc_h2(g1.x), bc_h2(g1.y)}, {bc_h2(g1.z), bc_h2(g1.w)} };
        #pragma unroll
        for (int p = 0; p < 4; ++p) {
            #pragma unroll
            for (int rh = 0; rh < 2; ++rh) {
                float a0 = __builtin_amdgcn_fdot2(ap[p][0], ga[2 * rh][0], 0.0f, false);
                a0 = __builtin_amdgcn_fdot2(ap[p][1], ga[2 * rh][1], a0, false);
                float a1 = __builtin_amdgcn_fdot2(ap[p][0], ga[2 * rh + 1][0], 0.0f, false);
                a1 = __builtin_amdgcn_fdot2(ap[p][1], ga[2 * rh + 1][1], a1, false);
                const int d0 = p * 4 + 2 * rh;
                SV[d0]     += a0;
                SV[d0 + 1] += a1;
                Vp[k][p * 2 + rh] = __builtin_amdgcn_cvt_pkrtz(a0, a1);
            }
        }
    }

    float b_log[9];                        // logits in log2 domain
    const int wv = tid >> 6;               // wave id 0..3

    // -------- iter 0: ck == 1/16 -> allreduce directly on SV --------
    {
        float s[16];
        #pragma unroll
        for (int d = 0; d < 16; ++d) s[d] = allred16(SV[d]);

        const float n2 = sumsq16(s) * (1.0f / 256.0f);               // ||S/16||^2
        const float g = n2 * __builtin_amdgcn_rcpf(1.0f + n2)
                           * __builtin_amdgcn_rsqf(n2 + CAPS_EPS);
        const float gl2 = g * (0.0625f * LOG2E);                     // log2-domain

        half2_t spk[8];
        #pragma unroll
        for (int j = 0; j < 8; ++j)
            spk[j] = __builtin_amdgcn_cvt_pkrtz(s[2 * j], s[2 * j + 1]);
        #pragma unroll
        for (int k = 0; k < 9; ++k) {
            float dot = 0.0f;
            #pragma unroll
            for (int j = 0; j < 8; ++j)
                dot = __builtin_amdgcn_fdot2(Vp[k][j], spk[j], dot, false);
            b_log[k] = gl2 * dot;
        }
    }

    // -------- iter 1: softmax + weighted accum + full allreduce --------
    {
        float eb[9], ebs[9];
        #pragma unroll
        for (int k = 0; k < 9; ++k) { eb[k] = EXP2(b_log[k]); ebs[k] = eb[k]; }
        #pragma unroll
        for (int k = 0; k < 9; ++k) {
            ebs[k] += xswap16(ebs[k], lane);           // xor16 (VALU permlane)
            ebs[k] += xswap32(ebs[k], lane);           // xor32 (VALU permlane)
        }
        if (lane < 16) {
            #pragma unroll
            for (int k = 0; k < 9; ++k)
                reinterpret_cast<float*>(&sbv[0][k * 16 + c])[wv] = ebs[k];
        }
        __syncthreads();
        float ck[9];
        #pragma unroll
        for (int k = 0; k < 9; ++k) {
            const float4 t = sbv[0][k * 16 + c];
            const float tot = (t.x + t.y) + (t.z + t.w);
            ck[k] = eb[k] * __builtin_amdgcn_rcpf(tot);
        }

        float s[16];
        #pragma unroll
        for (int d = 0; d < 16; ++d) s[d] = 0.0f;
        #pragma unroll
        for (int k = 0; k < 9; ++k) {
            const float ckk = ck[k];
            #pragma unroll
            for (int j = 0; j < 8; ++j) {
                fmamix_lo(s[2 * j],     ckk, Vp[k][j]);
                fmamix_hi(s[2 * j + 1], ckk, Vp[k][j]);
            }
        }
        #pragma unroll
        for (int d = 0; d < 16; ++d) s[d] = allred16(s[d]);

        const float n2S = sumsq16(s);
        const float g = n2S * __builtin_amdgcn_rcpf(1.0f + n2S)
                            * __builtin_amdgcn_rsqf(n2S + CAPS_EPS);
        const float gl2 = g * LOG2E;

        half2_t spk[8];
        #pragma unroll
        for (int j = 0; j < 8; ++j)
            spk[j] = __builtin_amdgcn_cvt_pkrtz(s[2 * j], s[2 * j + 1]);
        #pragma unroll
        for (int k = 0; k < 9; ++k) {
            float dot = 0.0f;
            #pragma unroll
            for (int j = 0; j < 8; ++j)
                dot = __builtin_amdgcn_fdot2(Vp[k][j], spk[j], dot, false);
            b_log[k] = fmaf(gl2, dot, b_log[k]);
        }
    }

    // -------- iter 2: reduce-scatter (lane c keeps s[c]), no allgather --------
    {
        float eb[9], ebs[9];
        #pragma unroll
        for (int k = 0; k < 9; ++k) { eb[k] = EXP2(b_log[k]); ebs[k] = eb[k]; }
        #pragma unroll
        for (int k = 0; k < 9; ++k) {
            ebs[k] += xswap16(ebs[k], lane);
            ebs[k] += xswap32(ebs[k], lane);
        }
        if (lane < 16) {
            #pragma unroll
            for (int k = 0; k < 9; ++k)
                reinterpret_cast<float*>(&sbv[1][k * 16 + c])[wv] = ebs[k];
        }
        __syncthreads();
        float ck[9];
        #pragma unroll
        for (int k = 0; k < 9; ++k) {
            const float4 t = sbv[1][k * 16 + c];
            const float tot = (t.x + t.y) + (t.z + t.w);
            ck[k] = eb[k] * __builtin_amdgcn_rcpf(tot);
        }

        float s[16];
        #pragma unroll
        for (int d = 0; d < 16; ++d) s[d] = 0.0f;
        #pragma unroll
        for (int k = 0; k < 9; ++k) {
            const float ckk = ck[k];
            #pragma unroll
            for (int j = 0; j < 8; ++j) {
                fmamix_lo(s[2 * j],     ckk, Vp[k][j]);
                fmamix_hi(s[2 * j + 1], ckk, Vp[k][j]);
            }
        }
        // recursive-halving reduce-scatter: send the half the PARTNER keeps
        const bool k8 = (c & 8) != 0;
        float t8[8];
        #pragma unroll
        for (int j = 0; j < 8; ++j) {
            const float keep = k8 ? s[j + 8] : s[j];
            const float send = k8 ? s[j] : s[j + 8];
            t8[j] = keep + mov_dpp_f<0x128>(send);     // ror8 == xor8 within 16
        }
        const bool k4 = (c & 4) != 0;
        float t4[4];
        #pragma unroll
        for (int j = 0; j < 4; ++j) {
            const float keep = k4 ? t8[j + 4] : t8[j];
            const float send = k4 ? t8[j] : t8[j + 4];
            t4[j] = keep + mov_sw_f<0x101F>(send);     // exact xor4 (swizzle)
        }
        const bool k2 = (c & 2) != 0;
        float t2[2];
        #pragma unroll
        for (int j = 0; j < 2; ++j) {
            const float keep = k2 ? t4[j + 2] : t4[j];
            const float send = k2 ? t4[j] : t4[j + 2];
            t2[j] = keep + mov_dpp_f<0x4E>(send);
        }
        const bool k1 = (c & 1) != 0;
        const float z = (k1 ? t2[1] : t2[0]) + mov_dpp_f<0xB1>(k1 ? t2[0] : t2[1]);
        // z == fully-reduced s[c] on lane c

        const float n2 = allred16(z * z);              // ||s||^2 over the 16-group

        const float scale = n2 * __builtin_amdgcn_rcpf(1.0f + n2)
                               * __builtin_amdgcn_rsqf(n2 + CAPS_EPS);
        out[(size_t)pos * 256 + n * 16 + c] = z * scale;   // fully coalesced

        if (c == 0) {
            const float m2 = n2 * scale * scale;           // ||v||^2
            const float sc2 = m2 * __builtin_amdgcn_rcpf(1.0f + m2)
                                 * __builtin_amdgcn_rsqf(m2 + CAPS_EPS);
            out[921600 + (size_t)pos * 16 + n] = sqrtf(m2 * sc2 * sc2 + CAPS_EPS);
        }
    }
}

extern "C" void kernel_launch(void* const* d_in, const int* in_sizes, int n_in,
                              void* d_out, int out_size, void* d_ws, size_t ws_size,
                              hipStream_t stream) {
    const float* poses = (const float*)d_in[0];
    // d_in[1] = input_activations: unused by the reference computation
    const float* kern  = (const float*)d_in[2];
    float* out = (float*)d_out;
    half2_t* wpk = (half2_t*)d_ws;         // 73728 B of scratch

    pack_weights<<<dim3(144), dim3(256), 0, stream>>>(kern, wpk);
    caps_route<<<dim3(3600), dim3(256), 0, stream>>>(poses, wpk, out);
}